// Round 1
// baseline (561.877 us; speedup 1.0000x reference)
//
#include <hip/hip_runtime.h>
#include <math.h>

#define B_    32
#define C_    128
#define N_    64
#define HID_  256
#define PIX_  4096
#define STEEP 50.0f
#define INV_PI 0.318309886183790671f

// ---------------- K0: init score buffers with biases ----------------
__global__ void k0_init(float* __restrict__ row_s, float* __restrict__ col_s,
                        const float* __restrict__ b_row, const float* __restrict__ b_col) {
    int i = blockIdx.x * 256 + threadIdx.x;
    if (i < B_ * N_) row_s[i] = b_row[0];
    else {
        int j = i - B_ * N_;
        if (j < B_ * N_) col_s[j] = b_col[0];
    }
}

// ---------------- K1: conv1  h1 = relu(w1 @ x + b1) ----------------
// Per batch GEMM: M=256 (o), K=128 (c), N=4096 (pix). Block tile 128x128, thread 8x8.
__global__ __launch_bounds__(256) void k1_conv1(const float* __restrict__ x,
                                                const float* __restrict__ w1,
                                                const float* __restrict__ b1,
                                                float* __restrict__ h1) {
    __shared__ __align__(16) float As[16 * 132];  // [k][o] padded
    __shared__ __align__(16) float Bs[16 * 132];  // [k][p] padded
    const int t = threadIdx.x;
    const int tx = t & 15, ty = t >> 4;
    const int pbase = blockIdx.x * 128;
    const int obase = blockIdx.y * 128;
    const int b = blockIdx.z;
    const float* xb = x + (size_t)b * C_ * PIX_;

    float acc[2][4][2][4];
#pragma unroll
    for (int a = 0; a < 2; a++)
#pragma unroll
        for (int i = 0; i < 4; i++)
#pragma unroll
            for (int p = 0; p < 2; p++)
#pragma unroll
                for (int j = 0; j < 4; j++) acc[a][i][p][j] = 0.f;

    for (int c0 = 0; c0 < C_; c0 += 16) {
        // stage A: w1 tile [128 o][16 k] -> As[k][o] (transposed)
#pragma unroll
        for (int r = 0; r < 2; r++) {
            int idx = t + r * 256;               // f4 index 0..511
            int oo = idx >> 2, q = idx & 3;
            float4 v = *(const float4*)&w1[(obase + oo) * C_ + c0 + q * 4];
            As[(q * 4 + 0) * 132 + oo] = v.x;
            As[(q * 4 + 1) * 132 + oo] = v.y;
            As[(q * 4 + 2) * 132 + oo] = v.z;
            As[(q * 4 + 3) * 132 + oo] = v.w;
        }
        // stage B: x tile [16 k][128 p] -> Bs[k][p]
#pragma unroll
        for (int r = 0; r < 2; r++) {
            int idx = t + r * 256;
            int kk = idx >> 5, pq = idx & 31;
            float4 v = *(const float4*)&xb[(size_t)(c0 + kk) * PIX_ + pbase + pq * 4];
            *(float4*)&Bs[kk * 132 + pq * 4] = v;
        }
        __syncthreads();
#pragma unroll
        for (int k = 0; k < 16; k++) {
            float4 a0 = *(const float4*)&As[k * 132 + ty * 4];
            float4 a1 = *(const float4*)&As[k * 132 + 64 + ty * 4];
            float4 b0 = *(const float4*)&Bs[k * 132 + tx * 4];
            float4 b1f = *(const float4*)&Bs[k * 132 + 64 + tx * 4];
            float av[2][4] = {{a0.x, a0.y, a0.z, a0.w}, {a1.x, a1.y, a1.z, a1.w}};
            float bv[2][4] = {{b0.x, b0.y, b0.z, b0.w}, {b1f.x, b1f.y, b1f.z, b1f.w}};
#pragma unroll
            for (int oh = 0; oh < 2; oh++)
#pragma unroll
                for (int di = 0; di < 4; di++)
#pragma unroll
                    for (int ph = 0; ph < 2; ph++)
#pragma unroll
                        for (int dj = 0; dj < 4; dj++)
                            acc[oh][di][ph][dj] += av[oh][di] * bv[ph][dj];
        }
        __syncthreads();
    }
#pragma unroll
    for (int oh = 0; oh < 2; oh++)
#pragma unroll
        for (int di = 0; di < 4; di++) {
            int o = obase + oh * 64 + ty * 4 + di;
            float bias = b1[o];
            float* dst = h1 + ((size_t)b * HID_ + o) * PIX_ + pbase;
#pragma unroll
            for (int ph = 0; ph < 2; ph++) {
                float4 v;
                v.x = fmaxf(acc[oh][di][ph][0] + bias, 0.f);
                v.y = fmaxf(acc[oh][di][ph][1] + bias, 0.f);
                v.z = fmaxf(acc[oh][di][ph][2] + bias, 0.f);
                v.w = fmaxf(acc[oh][di][ph][3] + bias, 0.f);
                *(float4*)&dst[ph * 64 + tx * 4] = v;
            }
        }
}

// ---------------- K2: conv2 + fused score reductions ----------------
// h2 = relu(w2 @ h1 + b2) computed in registers only; scores accumulated.
__global__ __launch_bounds__(256) void k2_conv2_scores(
    const float* __restrict__ h1, const float* __restrict__ w2,
    const float* __restrict__ b2, const float* __restrict__ w_row,
    const float* __restrict__ w_col, float* __restrict__ row_s,
    float* __restrict__ col_s) {
    __shared__ __align__(16) float As[16 * 132];
    __shared__ __align__(16) float Bs[16 * 132];
    __shared__ float col_red[64];
    __shared__ float row_red[2];
    const int t = threadIdx.x;
    const int tx = t & 15, ty = t >> 4;
    const int pbase = blockIdx.x * 128;
    const int obase = blockIdx.y * 128;
    const int bb_ = blockIdx.z;
    const float* h1b = h1 + (size_t)bb_ * HID_ * PIX_;

    float acc[2][4][2][4];
#pragma unroll
    for (int a = 0; a < 2; a++)
#pragma unroll
        for (int i = 0; i < 4; i++)
#pragma unroll
            for (int p = 0; p < 2; p++)
#pragma unroll
                for (int j = 0; j < 4; j++) acc[a][i][p][j] = 0.f;

    for (int c0 = 0; c0 < HID_; c0 += 16) {
#pragma unroll
        for (int r = 0; r < 2; r++) {
            int idx = t + r * 256;
            int oo = idx >> 2, q = idx & 3;
            float4 v = *(const float4*)&w2[(obase + oo) * HID_ + c0 + q * 4];
            As[(q * 4 + 0) * 132 + oo] = v.x;
            As[(q * 4 + 1) * 132 + oo] = v.y;
            As[(q * 4 + 2) * 132 + oo] = v.z;
            As[(q * 4 + 3) * 132 + oo] = v.w;
        }
#pragma unroll
        for (int r = 0; r < 2; r++) {
            int idx = t + r * 256;
            int kk = idx >> 5, pq = idx & 31;
            float4 v = *(const float4*)&h1b[(size_t)(c0 + kk) * PIX_ + pbase + pq * 4];
            *(float4*)&Bs[kk * 132 + pq * 4] = v;
        }
        __syncthreads();
#pragma unroll
        for (int k = 0; k < 16; k++) {
            float4 a0 = *(const float4*)&As[k * 132 + ty * 4];
            float4 a1 = *(const float4*)&As[k * 132 + 64 + ty * 4];
            float4 b0 = *(const float4*)&Bs[k * 132 + tx * 4];
            float4 b1f = *(const float4*)&Bs[k * 132 + 64 + tx * 4];
            float av[2][4] = {{a0.x, a0.y, a0.z, a0.w}, {a1.x, a1.y, a1.z, a1.w}};
            float bv[2][4] = {{b0.x, b0.y, b0.z, b0.w}, {b1f.x, b1f.y, b1f.z, b1f.w}};
#pragma unroll
            for (int oh = 0; oh < 2; oh++)
#pragma unroll
                for (int di = 0; di < 4; di++)
#pragma unroll
                    for (int ph = 0; ph < 2; ph++)
#pragma unroll
                        for (int dj = 0; dj < 4; dj++)
                            acc[oh][di][ph][dj] += av[oh][di] * bv[ph][dj];
        }
        __syncthreads();
    }

    // epilogue: h2 -> score partials (h2 never touches memory)
    const int h0 = pbase >> 6;  // block spans rows h0, h0+1
    float rpart[2] = {0.f, 0.f};
    float cpart[4] = {0.f, 0.f, 0.f, 0.f};
#pragma unroll
    for (int oh = 0; oh < 2; oh++)
#pragma unroll
        for (int di = 0; di < 4; di++) {
            int o = obase + oh * 64 + ty * 4 + di;
            float bias = b2[o];
            float wr[4];
#pragma unroll
            for (int dj = 0; dj < 4; dj++) wr[dj] = w_row[o * N_ + tx * 4 + dj];
            float wc0 = w_col[o * N_ + h0];
            float wc1 = w_col[o * N_ + h0 + 1];
#pragma unroll
            for (int ph = 0; ph < 2; ph++) {
                float wch = ph ? wc1 : wc0;
#pragma unroll
                for (int dj = 0; dj < 4; dj++) {
                    float v = fmaxf(acc[oh][di][ph][dj] + bias, 0.f);
                    rpart[ph] += v * wr[dj];
                    cpart[dj] += v * wch;
                }
            }
        }

    if (t < 64) col_red[t] = 0.f;
    if (t < 2) row_red[t] = 0.f;
    __syncthreads();
    int lane = t & 63;
    float r0 = rpart[0], r1 = rpart[1];
#pragma unroll
    for (int off = 32; off; off >>= 1) {
        r0 += __shfl_xor(r0, off, 64);
        r1 += __shfl_xor(r1, off, 64);
    }
    if (lane == 0) {
        atomicAdd(&row_red[0], r0);
        atomicAdd(&row_red[1], r1);
    }
#pragma unroll
    for (int dj = 0; dj < 4; dj++) {
        float cp = cpart[dj];
        cp += __shfl_xor(cp, 16, 64);
        cp += __shfl_xor(cp, 32, 64);
        if (lane < 16) atomicAdd(&col_red[lane * 4 + dj], cp);
    }
    __syncthreads();
    if (t < 64) atomicAdd(&col_s[bb_ * N_ + t], col_red[t]);
    if (t < 2) atomicAdd(&row_s[bb_ * N_ + h0 + t], row_red[t]);
}

// ---------------- K4: differentiable bitonic sort -> P matrices ----------------
__global__ __launch_bounds__(64) void k4_diffsort(const float* __restrict__ row_s,
                                                  const float* __restrict__ col_s,
                                                  float* __restrict__ p_row,
                                                  float* __restrict__ p_col) {
    __shared__ float Ps[64 * 65];
    __shared__ float xs[64];
    __shared__ float als[32];
    const int t = threadIdx.x;
    const int which = blockIdx.x & 1;
    const int b = blockIdx.x >> 1;
    const float* sc = which ? col_s : row_s;
    float* Pout = which ? p_col : p_row;

    xs[t] = sc[b * 64 + t];
#pragma unroll
    for (int i = 0; i < 64; i++) Ps[i * 65 + t] = (i == t) ? 1.f : 0.f;
    __syncthreads();

    for (int bl = 0; bl < 6; bl++) {
        for (int ly = 0; ly <= bl; ly++) {
            int sh = bl - ly;
            int m = 1 << sh;
            if (t < 32) {
                int i = (t >> sh) << (sh + 1);
                int j = t & (m - 1);
                int ix = i + j;
                int a = ix, bidx = ix + m;
                if ((ix >> (bl + 1)) & 1) { int tmp = a; a = bidx; bidx = tmp; }
                float xa = xs[a], xbv = xs[bidx];
                float al = atanf((xbv - xa) * STEEP) * INV_PI + 0.5f;
                als[t] = al;
                xs[a] = al * xa + (1.f - al) * xbv;
                xs[bidx] = (1.f - al) * xa + al * xbv;
            }
            __syncthreads();
            // every thread updates its row t of P
            for (int p = 0; p < 32; p++) {
                int i = (p >> sh) << (sh + 1);
                int j = p & (m - 1);
                int ix = i + j;
                int a = ix, bidx = ix + m;
                if ((ix >> (bl + 1)) & 1) { int tmp = a; a = bidx; bidx = tmp; }
                float al = als[p];
                float Pa = Ps[t * 65 + a], Pb = Ps[t * 65 + bidx];
                Ps[t * 65 + a] = al * Pa + (1.f - al) * Pb;
                Ps[t * 65 + bidx] = (1.f - al) * Pa + al * Pb;
            }
            __syncthreads();
        }
    }
    for (int i = 0; i < 64; i++) Pout[(b * 64 + i) * 64 + t] = Ps[i * 65 + t];
}

// ---------------- K5: fused  out = P_col @ (P_row @ x)^T-style double permute ----
// stage1: y[i][k] = sum_j Prow[i][j] * x[b,c,j,k]
// stage2: out[i][k] = sum_j Pcol[i][j] * y[k][j]   (via Y2[j][k] = y[k][j])
__global__ __launch_bounds__(128) void k5_permute(const float* __restrict__ x,
                                                  const float* __restrict__ p_row,
                                                  const float* __restrict__ p_col,
                                                  float* __restrict__ out) {
    __shared__ __align__(16) float Ptr[64 * 64];  // Prow transposed [j][i]
    __shared__ __align__(16) float Ptc[64 * 64];  // Pcol transposed [j][i]
    __shared__ __align__(16) float Y2[2][64 * 64];
    const int t = threadIdx.x;
    const int b = blockIdx.y;
    const int w = t >> 6, l = t & 63;
    const int ti = l >> 3, tk = l & 7;
    const int c = blockIdx.x * 2 + w;

    const float* Pr = p_row + b * 4096;
    const float* Pc = p_col + b * 4096;
#pragma unroll
    for (int r = 0; r < 8; r++) {
        int f4i = t + r * 128;  // 0..1023
        int i = f4i >> 4, j0 = (f4i & 15) * 4;
        float4 v = *(const float4*)&Pr[i * 64 + j0];
        Ptr[(j0 + 0) * 64 + i] = v.x;
        Ptr[(j0 + 1) * 64 + i] = v.y;
        Ptr[(j0 + 2) * 64 + i] = v.z;
        Ptr[(j0 + 3) * 64 + i] = v.w;
        float4 u = *(const float4*)&Pc[i * 64 + j0];
        Ptc[(j0 + 0) * 64 + i] = u.x;
        Ptc[(j0 + 1) * 64 + i] = u.y;
        Ptc[(j0 + 2) * 64 + i] = u.z;
        Ptc[(j0 + 3) * 64 + i] = u.w;
    }
    __syncthreads();

    const float* xc = x + ((size_t)b * C_ + c) * PIX_;
    float acc[8][8];
#pragma unroll
    for (int i = 0; i < 8; i++)
#pragma unroll
        for (int j = 0; j < 8; j++) acc[i][j] = 0.f;

    for (int j = 0; j < 64; j++) {
        float4 p0 = *(const float4*)&Ptr[j * 64 + ti * 8];
        float4 p1 = *(const float4*)&Ptr[j * 64 + ti * 8 + 4];
        float4 x0 = *(const float4*)&xc[j * 64 + tk * 8];
        float4 x1 = *(const float4*)&xc[j * 64 + tk * 8 + 4];
        float pv[8] = {p0.x, p0.y, p0.z, p0.w, p1.x, p1.y, p1.z, p1.w};
        float xv[8] = {x0.x, x0.y, x0.z, x0.w, x1.x, x1.y, x1.z, x1.w};
#pragma unroll
        for (int di = 0; di < 8; di++)
#pragma unroll
            for (int dk = 0; dk < 8; dk++) acc[di][dk] += pv[di] * xv[dk];
    }
#pragma unroll
    for (int dk = 0; dk < 8; dk++) {
        float4 v0 = {acc[0][dk], acc[1][dk], acc[2][dk], acc[3][dk]};
        float4 v1 = {acc[4][dk], acc[5][dk], acc[6][dk], acc[7][dk]};
        *(float4*)&Y2[w][(tk * 8 + dk) * 64 + ti * 8] = v0;
        *(float4*)&Y2[w][(tk * 8 + dk) * 64 + ti * 8 + 4] = v1;
    }
    __syncthreads();

    float acc2[8][8];
#pragma unroll
    for (int i = 0; i < 8; i++)
#pragma unroll
        for (int j = 0; j < 8; j++) acc2[i][j] = 0.f;

    for (int j = 0; j < 64; j++) {
        float4 p0 = *(const float4*)&Ptc[j * 64 + ti * 8];
        float4 p1 = *(const float4*)&Ptc[j * 64 + ti * 8 + 4];
        float4 y0 = *(const float4*)&Y2[w][j * 64 + tk * 8];
        float4 y1 = *(const float4*)&Y2[w][j * 64 + tk * 8 + 4];
        float pv[8] = {p0.x, p0.y, p0.z, p0.w, p1.x, p1.y, p1.z, p1.w};
        float yv[8] = {y0.x, y0.y, y0.z, y0.w, y1.x, y1.y, y1.z, y1.w};
#pragma unroll
        for (int di = 0; di < 8; di++)
#pragma unroll
            for (int dk = 0; dk < 8; dk++) acc2[di][dk] += pv[di] * yv[dk];
    }
    float* oc = out + ((size_t)b * C_ + c) * PIX_;
#pragma unroll
    for (int di = 0; di < 8; di++) {
        float4 v0 = {acc2[di][0], acc2[di][1], acc2[di][2], acc2[di][3]};
        float4 v1 = {acc2[di][4], acc2[di][5], acc2[di][6], acc2[di][7]};
        *(float4*)&oc[(ti * 8 + di) * 64 + tk * 8] = v0;
        *(float4*)&oc[(ti * 8 + di) * 64 + tk * 8 + 4] = v1;
    }
}

extern "C" void kernel_launch(void* const* d_in, const int* in_sizes, int n_in,
                              void* d_out, int out_size, void* d_ws, size_t ws_size,
                              hipStream_t stream) {
    const float* x = (const float*)d_in[0];
    const float* w1 = (const float*)d_in[1];
    const float* b1 = (const float*)d_in[2];
    const float* w2 = (const float*)d_in[3];
    const float* b2 = (const float*)d_in[4];
    const float* w_row = (const float*)d_in[5];
    const float* b_row = (const float*)d_in[6];
    const float* w_col = (const float*)d_in[7];
    const float* b_col = (const float*)d_in[8];
    float* out = (float*)d_out;

    float* ws = (float*)d_ws;
    float* h1 = ws;                         // 32*256*4096 = 33554432 floats
    float* row_s = ws + 33554432;           // 2048
    float* col_s = row_s + 2048;            // 2048
    float* p_row = col_s + 2048;            // 131072
    float* p_col = p_row + 131072;          // 131072

    hipLaunchKernelGGL(k0_init, dim3(16), dim3(256), 0, stream, row_s, col_s, b_row, b_col);
    hipLaunchKernelGGL(k1_conv1, dim3(32, 2, 32), dim3(256), 0, stream, x, w1, b1, h1);
    hipLaunchKernelGGL(k2_conv2_scores, dim3(32, 2, 32), dim3(256), 0, stream,
                       h1, w2, b2, w_row, w_col, row_s, col_s);
    hipLaunchKernelGGL(k4_diffsort, dim3(64), dim3(64), 0, stream, row_s, col_s, p_row, p_col);
    hipLaunchKernelGGL(k5_permute, dim3(64, 32), dim3(128), 0, stream, x, p_row, p_col, out);
}

// Round 2
// 421.960 us; speedup vs baseline: 1.3316x; 1.3316x over previous
//
#include <hip/hip_runtime.h>
#include <math.h>

#define B_    32
#define C_    128
#define N_    64
#define HID_  256
#define PIX_  4096
#define STEEP 50.0f
#define INV_PI 0.318309886183790671f
#define LDA   40   // LDS row pitch in bf16 (32 data + 8 pad; 80B = 20 banks -> 2-way reads, free)

typedef unsigned short u16;
typedef __attribute__((ext_vector_type(8))) short bf16x8;
typedef __attribute__((ext_vector_type(4))) float f32x4;

__device__ __forceinline__ u16 f2bf(float f) {
    unsigned int u = __builtin_bit_cast(unsigned int, f);
    unsigned int r = (u + 0x7FFFu + ((u >> 16) & 1u)) >> 16;
    return (u16)r;
}
__device__ __forceinline__ float bf2f(u16 h) {
    unsigned int u = ((unsigned int)h) << 16;
    return __builtin_bit_cast(float, u);
}

// ---------------- K0: init score buffers with biases ----------------
__global__ void k0_init(float* __restrict__ row_s, float* __restrict__ col_s,
                        const float* __restrict__ b_row, const float* __restrict__ b_col) {
    int i = blockIdx.x * 256 + threadIdx.x;
    if (i < B_ * N_) row_s[i] = b_row[0];
    else {
        int j = i - B_ * N_;
        if (j < B_ * N_) col_s[j] = b_col[0];
    }
}

// ---------------- Kprep: decompose weights into bf16 hi/lo ----------------
__global__ void k_prep(const float* __restrict__ w1, const float* __restrict__ w2,
                       u16* __restrict__ w1h, u16* __restrict__ w1l,
                       u16* __restrict__ w2h, u16* __restrict__ w2l) {
    int i = blockIdx.x * 256 + threadIdx.x;
    if (i < HID_ * C_) {
        float v = w1[i];
        u16 h = f2bf(v);
        w1h[i] = h;
        w1l[i] = f2bf(v - bf2f(h));
    } else {
        int j = i - HID_ * C_;
        if (j < HID_ * HID_) {
            float v = w2[j];
            u16 h = f2bf(v);
            w2h[j] = h;
            w2l[j] = f2bf(v - bf2f(h));
        }
    }
}

// ---------------- K1: conv1 via bf16x2 MFMA ----------------
// C[o,p] = sum_c w1[o,c] x[b,c,p];  h1 = relu(C+b1) stored as bf16 hi/lo in [b][p][o]
__global__ __launch_bounds__(256) void k1_conv1(const float* __restrict__ x,
                                                const u16* __restrict__ w1h,
                                                const u16* __restrict__ w1l,
                                                const float* __restrict__ b1,
                                                u16* __restrict__ h1h,
                                                u16* __restrict__ h1l) {
    __shared__ __align__(16) u16 Ah[128 * LDA];
    __shared__ __align__(16) u16 Al[128 * LDA];
    __shared__ __align__(16) u16 Bh[128 * LDA];
    __shared__ __align__(16) u16 Bl[128 * LDA];
    const int t = threadIdx.x;
    const int l = t & 63, wv = t >> 6;
    const int row = l & 15, q = l >> 4;
    const int pbase = blockIdx.x * 128, obase = blockIdx.y * 128, b = blockIdx.z;
    const int mwave = (wv & 1) * 64, nwave = (wv >> 1) * 64;
    const float* xb = x + (size_t)b * C_ * PIX_ + pbase;

    f32x4 acc[4][4];
#pragma unroll
    for (int i = 0; i < 4; i++)
#pragma unroll
        for (int j = 0; j < 4; j++) acc[i][j] = (f32x4){0.f, 0.f, 0.f, 0.f};

    for (int k0 = 0; k0 < C_; k0 += 32) {
        // stage A: weights [o][k] hi/lo, direct copy (k-contiguous)
        {
            int o = t >> 1, hf = t & 1;
            const float4* sh = (const float4*)&w1h[(size_t)(obase + o) * C_ + k0 + hf * 16];
            const float4* sl = (const float4*)&w1l[(size_t)(obase + o) * C_ + k0 + hf * 16];
            float4 vh0 = sh[0], vh1 = sh[1];
            float4 vl0 = sl[0], vl1 = sl[1];
            *(float4*)&Ah[o * LDA + hf * 16] = vh0;
            *(float4*)&Ah[o * LDA + hf * 16 + 8] = vh1;
            *(float4*)&Al[o * LDA + hf * 16] = vl0;
            *(float4*)&Al[o * LDA + hf * 16 + 8] = vl1;
        }
        // stage B: x [c][p] -> LDS [p][c] with hi/lo decompose (transpose)
        {
            int cp = t & 15, pg = t >> 4;
            int c = k0 + cp * 2;
            float4 a0 = *(const float4*)&xb[(size_t)c * PIX_ + pg * 8];
            float4 a1 = *(const float4*)&xb[(size_t)c * PIX_ + pg * 8 + 4];
            float4 c0v = *(const float4*)&xb[(size_t)(c + 1) * PIX_ + pg * 8];
            float4 c1v = *(const float4*)&xb[(size_t)(c + 1) * PIX_ + pg * 8 + 4];
            float va[8] = {a0.x, a0.y, a0.z, a0.w, a1.x, a1.y, a1.z, a1.w};
            float vb[8] = {c0v.x, c0v.y, c0v.z, c0v.w, c1v.x, c1v.y, c1v.z, c1v.w};
#pragma unroll
            for (int j = 0; j < 8; j++) {
                u16 h0 = f2bf(va[j]), h1v = f2bf(vb[j]);
                u16 l0 = f2bf(va[j] - bf2f(h0)), l1 = f2bf(vb[j] - bf2f(h1v));
                *(unsigned int*)&Bh[(pg * 8 + j) * LDA + cp * 2] =
                    (unsigned int)h0 | ((unsigned int)h1v << 16);
                *(unsigned int*)&Bl[(pg * 8 + j) * LDA + cp * 2] =
                    (unsigned int)l0 | ((unsigned int)l1 << 16);
            }
        }
        __syncthreads();

        bf16x8 afh[4], afl[4], bfh[4], bfl[4];
#pragma unroll
        for (int mf = 0; mf < 4; mf++) {
            afh[mf] = *(const bf16x8*)&Ah[(mwave + mf * 16 + row) * LDA + q * 8];
            afl[mf] = *(const bf16x8*)&Al[(mwave + mf * 16 + row) * LDA + q * 8];
        }
#pragma unroll
        for (int nf = 0; nf < 4; nf++) {
            bfh[nf] = *(const bf16x8*)&Bh[(nwave + nf * 16 + row) * LDA + q * 8];
            bfl[nf] = *(const bf16x8*)&Bl[(nwave + nf * 16 + row) * LDA + q * 8];
        }
#pragma unroll
        for (int mf = 0; mf < 4; mf++)
#pragma unroll
            for (int nf = 0; nf < 4; nf++) {
                acc[mf][nf] = __builtin_amdgcn_mfma_f32_16x16x32_bf16(afh[mf], bfh[nf], acc[mf][nf], 0, 0, 0);
                acc[mf][nf] = __builtin_amdgcn_mfma_f32_16x16x32_bf16(afh[mf], bfl[nf], acc[mf][nf], 0, 0, 0);
                acc[mf][nf] = __builtin_amdgcn_mfma_f32_16x16x32_bf16(afl[mf], bfh[nf], acc[mf][nf], 0, 0, 0);
            }
        __syncthreads();
    }

    // epilogue: relu(acc + b1) -> decompose -> h1 hi/lo at [b][p][o]
#pragma unroll
    for (int mf = 0; mf < 4; mf++) {
        int o = obase + mwave + mf * 16 + q * 4;
        float bias[4];
#pragma unroll
        for (int r = 0; r < 4; r++) bias[r] = b1[o + r];
#pragma unroll
        for (int nf = 0; nf < 4; nf++) {
            int p = pbase + nwave + nf * 16 + row;
            u16 hh[4], ll[4];
#pragma unroll
            for (int r = 0; r < 4; r++) {
                float v = fmaxf(acc[mf][nf][r] + bias[r], 0.f);
                u16 h = f2bf(v);
                hh[r] = h;
                ll[r] = f2bf(v - bf2f(h));
            }
            size_t base = ((size_t)b * PIX_ + p) * HID_ + o;
            *(unsigned long long*)&h1h[base] =
                (unsigned long long)hh[0] | ((unsigned long long)hh[1] << 16) |
                ((unsigned long long)hh[2] << 32) | ((unsigned long long)hh[3] << 48);
            *(unsigned long long*)&h1l[base] =
                (unsigned long long)ll[0] | ((unsigned long long)ll[1] << 16) |
                ((unsigned long long)ll[2] << 32) | ((unsigned long long)ll[3] << 48);
        }
    }
}

// ---------------- K2: conv2 via bf16x2 MFMA + fused score reductions ----------------
__global__ __launch_bounds__(256) void k2_conv2_scores(
    const u16* __restrict__ h1h, const u16* __restrict__ h1l,
    const u16* __restrict__ w2h, const u16* __restrict__ w2l,
    const float* __restrict__ b2, const float* __restrict__ w_row,
    const float* __restrict__ w_col, float* __restrict__ row_s,
    float* __restrict__ col_s) {
    __shared__ __align__(16) u16 Ah[128 * LDA];
    __shared__ __align__(16) u16 Al[128 * LDA];
    __shared__ __align__(16) u16 Bh[128 * LDA];
    __shared__ __align__(16) u16 Bl[128 * LDA];
    __shared__ float col_red[64];
    __shared__ float row_red[2];
    const int t = threadIdx.x;
    const int l = t & 63, wv = t >> 6;
    const int row = l & 15, q = l >> 4;
    const int pbase = blockIdx.x * 128, obase = blockIdx.y * 128, b = blockIdx.z;
    const int mwave = (wv & 1) * 64, nwave = (wv >> 1) * 64;

    if (t < 64) col_red[t] = 0.f;
    if (t < 2) row_red[t] = 0.f;

    f32x4 acc[4][4];
#pragma unroll
    for (int i = 0; i < 4; i++)
#pragma unroll
        for (int j = 0; j < 4; j++) acc[i][j] = (f32x4){0.f, 0.f, 0.f, 0.f};

    for (int k0 = 0; k0 < HID_; k0 += 32) {
        {
            int o = t >> 1, hf = t & 1;
            const float4* sh = (const float4*)&w2h[(size_t)(obase + o) * HID_ + k0 + hf * 16];
            const float4* sl = (const float4*)&w2l[(size_t)(obase + o) * HID_ + k0 + hf * 16];
            float4 vh0 = sh[0], vh1 = sh[1];
            float4 vl0 = sl[0], vl1 = sl[1];
            *(float4*)&Ah[o * LDA + hf * 16] = vh0;
            *(float4*)&Ah[o * LDA + hf * 16 + 8] = vh1;
            *(float4*)&Al[o * LDA + hf * 16] = vl0;
            *(float4*)&Al[o * LDA + hf * 16 + 8] = vl1;
        }
        {
            int p = t >> 1, hf = t & 1;
            size_t base = ((size_t)b * PIX_ + pbase + p) * HID_ + k0 + hf * 16;
            const float4* sh = (const float4*)&h1h[base];
            const float4* sl = (const float4*)&h1l[base];
            float4 vh0 = sh[0], vh1 = sh[1];
            float4 vl0 = sl[0], vl1 = sl[1];
            *(float4*)&Bh[p * LDA + hf * 16] = vh0;
            *(float4*)&Bh[p * LDA + hf * 16 + 8] = vh1;
            *(float4*)&Bl[p * LDA + hf * 16] = vl0;
            *(float4*)&Bl[p * LDA + hf * 16 + 8] = vl1;
        }
        __syncthreads();

        bf16x8 afh[4], afl[4], bfh[4], bfl[4];
#pragma unroll
        for (int mf = 0; mf < 4; mf++) {
            afh[mf] = *(const bf16x8*)&Ah[(mwave + mf * 16 + row) * LDA + q * 8];
            afl[mf] = *(const bf16x8*)&Al[(mwave + mf * 16 + row) * LDA + q * 8];
        }
#pragma unroll
        for (int nf = 0; nf < 4; nf++) {
            bfh[nf] = *(const bf16x8*)&Bh[(nwave + nf * 16 + row) * LDA + q * 8];
            bfl[nf] = *(const bf16x8*)&Bl[(nwave + nf * 16 + row) * LDA + q * 8];
        }
#pragma unroll
        for (int mf = 0; mf < 4; mf++)
#pragma unroll
            for (int nf = 0; nf < 4; nf++) {
                acc[mf][nf] = __builtin_amdgcn_mfma_f32_16x16x32_bf16(afh[mf], bfh[nf], acc[mf][nf], 0, 0, 0);
                acc[mf][nf] = __builtin_amdgcn_mfma_f32_16x16x32_bf16(afh[mf], bfl[nf], acc[mf][nf], 0, 0, 0);
                acc[mf][nf] = __builtin_amdgcn_mfma_f32_16x16x32_bf16(afl[mf], bfh[nf], acc[mf][nf], 0, 0, 0);
            }
        __syncthreads();
    }

    // epilogue: h2 = relu(acc + b2); accumulate scores (h2 never hits memory)
    const int h0 = pbase >> 6;          // block spans rows h0 (waves 0,1) and h0+1 (waves 2,3)
    const int h = h0 + (wv >> 1);
    float rpart = 0.f;
    float cpart[4] = {0.f, 0.f, 0.f, 0.f};
#pragma unroll
    for (int mf = 0; mf < 4; mf++) {
        int o = obase + mwave + mf * 16 + q * 4;
#pragma unroll
        for (int r = 0; r < 4; r++) {
            float bias = b2[o + r];
            float wcv = w_col[(o + r) * N_ + h];
#pragma unroll
            for (int nf = 0; nf < 4; nf++) {
                int w = nf * 16 + row;
                float v = fmaxf(acc[mf][nf][r] + bias, 0.f);
                rpart += v * w_row[(o + r) * N_ + w];
                cpart[nf] += v * wcv;
            }
        }
    }
    __syncthreads();
#pragma unroll
    for (int off = 32; off; off >>= 1) rpart += __shfl_xor(rpart, off, 64);
    if (l == 0) atomicAdd(&row_red[wv >> 1], rpart);
#pragma unroll
    for (int nf = 0; nf < 4; nf++) {
        float cp = cpart[nf];
        cp += __shfl_xor(cp, 16, 64);
        cp += __shfl_xor(cp, 32, 64);
        if (l < 16) atomicAdd(&col_red[nf * 16 + l], cp);
    }
    __syncthreads();
    if (t < 64) atomicAdd(&col_s[b * N_ + t], col_red[t]);
    if (t < 2) atomicAdd(&row_s[b * N_ + h0 + t], row_red[t]);
}

// ---------------- K4: differentiable bitonic sort -> P matrices ----------------
__global__ __launch_bounds__(64) void k4_diffsort(const float* __restrict__ row_s,
                                                  const float* __restrict__ col_s,
                                                  float* __restrict__ p_row,
                                                  float* __restrict__ p_col) {
    __shared__ float Ps[64 * 65];
    __shared__ float xs[64];
    __shared__ float als[32];
    const int t = threadIdx.x;
    const int which = blockIdx.x & 1;
    const int b = blockIdx.x >> 1;
    const float* sc = which ? col_s : row_s;
    float* Pout = which ? p_col : p_row;

    xs[t] = sc[b * 64 + t];
#pragma unroll
    for (int i = 0; i < 64; i++) Ps[i * 65 + t] = (i == t) ? 1.f : 0.f;
    __syncthreads();

    for (int bl = 0; bl < 6; bl++) {
        for (int ly = 0; ly <= bl; ly++) {
            int sh = bl - ly;
            int m = 1 << sh;
            if (t < 32) {
                int i = (t >> sh) << (sh + 1);
                int j = t & (m - 1);
                int ix = i + j;
                int a = ix, bidx = ix + m;
                if ((ix >> (bl + 1)) & 1) { int tmp = a; a = bidx; bidx = tmp; }
                float xa = xs[a], xbv = xs[bidx];
                float al = atanf((xbv - xa) * STEEP) * INV_PI + 0.5f;
                als[t] = al;
                xs[a] = al * xa + (1.f - al) * xbv;
                xs[bidx] = (1.f - al) * xa + al * xbv;
            }
            __syncthreads();
            for (int p = 0; p < 32; p++) {
                int i = (p >> sh) << (sh + 1);
                int j = p & (m - 1);
                int ix = i + j;
                int a = ix, bidx = ix + m;
                if ((ix >> (bl + 1)) & 1) { int tmp = a; a = bidx; bidx = tmp; }
                float al = als[p];
                float Pa = Ps[t * 65 + a], Pb = Ps[t * 65 + bidx];
                Ps[t * 65 + a] = al * Pa + (1.f - al) * Pb;
                Ps[t * 65 + bidx] = (1.f - al) * Pa + al * Pb;
            }
            __syncthreads();
        }
    }
    for (int i = 0; i < 64; i++) Pout[(b * 64 + i) * 64 + t] = Ps[i * 65 + t];
}

// ---------------- K5: fused double permutation ----------------
__global__ __launch_bounds__(128) void k5_permute(const float* __restrict__ x,
                                                  const float* __restrict__ p_row,
                                                  const float* __restrict__ p_col,
                                                  float* __restrict__ out) {
    __shared__ __align__(16) float Ptr[64 * 64];
    __shared__ __align__(16) float Ptc[64 * 64];
    __shared__ __align__(16) float Y2[2][64 * 64];
    const int t = threadIdx.x;
    const int b = blockIdx.y;
    const int w = t >> 6, l = t & 63;
    const int ti = l >> 3, tk = l & 7;
    const int c = blockIdx.x * 2 + w;

    const float* Pr = p_row + b * 4096;
    const float* Pc = p_col + b * 4096;
#pragma unroll
    for (int r = 0; r < 8; r++) {
        int f4i = t + r * 128;
        int i = f4i >> 4, j0 = (f4i & 15) * 4;
        float4 v = *(const float4*)&Pr[i * 64 + j0];
        Ptr[(j0 + 0) * 64 + i] = v.x;
        Ptr[(j0 + 1) * 64 + i] = v.y;
        Ptr[(j0 + 2) * 64 + i] = v.z;
        Ptr[(j0 + 3) * 64 + i] = v.w;
        float4 u = *(const float4*)&Pc[i * 64 + j0];
        Ptc[(j0 + 0) * 64 + i] = u.x;
        Ptc[(j0 + 1) * 64 + i] = u.y;
        Ptc[(j0 + 2) * 64 + i] = u.z;
        Ptc[(j0 + 3) * 64 + i] = u.w;
    }
    __syncthreads();

    const float* xc = x + ((size_t)b * C_ + c) * PIX_;
    float acc[8][8];
#pragma unroll
    for (int i = 0; i < 8; i++)
#pragma unroll
        for (int j = 0; j < 8; j++) acc[i][j] = 0.f;

    for (int j = 0; j < 64; j++) {
        float4 p0 = *(const float4*)&Ptr[j * 64 + ti * 8];
        float4 p1 = *(const float4*)&Ptr[j * 64 + ti * 8 + 4];
        float4 x0 = *(const float4*)&xc[j * 64 + tk * 8];
        float4 x1 = *(const float4*)&xc[j * 64 + tk * 8 + 4];
        float pv[8] = {p0.x, p0.y, p0.z, p0.w, p1.x, p1.y, p1.z, p1.w};
        float xv[8] = {x0.x, x0.y, x0.z, x0.w, x1.x, x1.y, x1.z, x1.w};
#pragma unroll
        for (int di = 0; di < 8; di++)
#pragma unroll
            for (int dk = 0; dk < 8; dk++) acc[di][dk] += pv[di] * xv[dk];
    }
#pragma unroll
    for (int dk = 0; dk < 8; dk++) {
        float4 v0 = {acc[0][dk], acc[1][dk], acc[2][dk], acc[3][dk]};
        float4 v1 = {acc[4][dk], acc[5][dk], acc[6][dk], acc[7][dk]};
        *(float4*)&Y2[w][(tk * 8 + dk) * 64 + ti * 8] = v0;
        *(float4*)&Y2[w][(tk * 8 + dk) * 64 + ti * 8 + 4] = v1;
    }
    __syncthreads();

    float acc2[8][8];
#pragma unroll
    for (int i = 0; i < 8; i++)
#pragma unroll
        for (int j = 0; j < 8; j++) acc2[i][j] = 0.f;

    for (int j = 0; j < 64; j++) {
        float4 p0 = *(const float4*)&Ptc[j * 64 + ti * 8];
        float4 p1 = *(const float4*)&Ptc[j * 64 + ti * 8 + 4];
        float4 y0 = *(const float4*)&Y2[w][j * 64 + tk * 8];
        float4 y1 = *(const float4*)&Y2[w][j * 64 + tk * 8 + 4];
        float pv[8] = {p0.x, p0.y, p0.z, p0.w, p1.x, p1.y, p1.z, p1.w};
        float yv[8] = {y0.x, y0.y, y0.z, y0.w, y1.x, y1.y, y1.z, y1.w};
#pragma unroll
        for (int di = 0; di < 8; di++)
#pragma unroll
            for (int dk = 0; dk < 8; dk++) acc2[di][dk] += pv[di] * yv[dk];
    }
    float* oc = out + ((size_t)b * C_ + c) * PIX_;
#pragma unroll
    for (int di = 0; di < 8; di++) {
        float4 v0 = {acc2[di][0], acc2[di][1], acc2[di][2], acc2[di][3]};
        float4 v1 = {acc2[di][4], acc2[di][5], acc2[di][6], acc2[di][7]};
        *(float4*)&oc[(ti * 8 + di) * 64 + tk * 8] = v0;
        *(float4*)&oc[(ti * 8 + di) * 64 + tk * 8 + 4] = v1;
    }
}

extern "C" void kernel_launch(void* const* d_in, const int* in_sizes, int n_in,
                              void* d_out, int out_size, void* d_ws, size_t ws_size,
                              hipStream_t stream) {
    const float* x = (const float*)d_in[0];
    const float* w1 = (const float*)d_in[1];
    const float* b1 = (const float*)d_in[2];
    const float* w2 = (const float*)d_in[3];
    const float* b2 = (const float*)d_in[4];
    const float* w_row = (const float*)d_in[5];
    const float* b_row = (const float*)d_in[6];
    const float* w_col = (const float*)d_in[7];
    const float* b_col = (const float*)d_in[8];
    float* out = (float*)d_out;

    char* ws = (char*)d_ws;
    u16* h1h = (u16*)(ws);                               //  67108864 B
    u16* h1l = (u16*)(ws + 67108864);                    //  67108864 B
    u16* w1h = (u16*)(ws + 134217728);                   //  65536 B
    u16* w1l = (u16*)(ws + 134283264);                   //  65536 B
    u16* w2h = (u16*)(ws + 134348800);                   //  131072 B
    u16* w2l = (u16*)(ws + 134479872);                   //  131072 B
    float* row_s = (float*)(ws + 134610944);             //  8192 B
    float* col_s = (float*)(ws + 134619136);             //  8192 B
    float* p_row = (float*)(ws + 134627328);             //  524288 B
    float* p_col = (float*)(ws + 135151616);             //  524288 B

    hipLaunchKernelGGL(k0_init, dim3(16), dim3(256), 0, stream, row_s, col_s, b_row, b_col);
    hipLaunchKernelGGL(k_prep, dim3(384), dim3(256), 0, stream, w1, w2, w1h, w1l, w2h, w2l);
    hipLaunchKernelGGL(k1_conv1, dim3(32, 2, 32), dim3(256), 0, stream, x, w1h, w1l, b1, h1h, h1l);
    hipLaunchKernelGGL(k2_conv2_scores, dim3(32, 2, 32), dim3(256), 0, stream,
                       h1h, h1l, w2h, w2l, b2, w_row, w_col, row_s, col_s);
    hipLaunchKernelGGL(k4_diffsort, dim3(64), dim3(64), 0, stream, row_s, col_s, p_row, p_col);
    hipLaunchKernelGGL(k5_permute, dim3(64, 32), dim3(128), 0, stream, x, p_row, p_col, out);
}

// Round 3
// 320.198 us; speedup vs baseline: 1.7548x; 1.3178x over previous
//
#include <hip/hip_runtime.h>
#include <math.h>

#define B_    32
#define C_    128
#define N_    64
#define HID_  256
#define PIX_  4096
#define STEEP 50.0f
#define INV_PI 0.318309886183790671f
#define LDA   40   // LDS row pitch in bf16 for 32-wide K tiles (k1/k2)
#define LDX   72   // LDS row pitch in bf16 for 64-wide rows (k5): 144B -> 2-way free

typedef unsigned short u16;
typedef __attribute__((ext_vector_type(8))) short bf16x8;
typedef __attribute__((ext_vector_type(4))) float f32x4;

__device__ __forceinline__ u16 f2bf(float f) {
    unsigned int u = __builtin_bit_cast(unsigned int, f);
    unsigned int r = (u + 0x7FFFu + ((u >> 16) & 1u)) >> 16;
    return (u16)r;
}
__device__ __forceinline__ float bf2f(u16 h) {
    unsigned int u = ((unsigned int)h) << 16;
    return __builtin_bit_cast(float, u);
}

// ---------------- K0: init score buffers with biases ----------------
__global__ void k0_init(float* __restrict__ row_s, float* __restrict__ col_s,
                        const float* __restrict__ b_row, const float* __restrict__ b_col) {
    int i = blockIdx.x * 256 + threadIdx.x;
    if (i < B_ * N_) row_s[i] = b_row[0];
    else {
        int j = i - B_ * N_;
        if (j < B_ * N_) col_s[j] = b_col[0];
    }
}

// ---------------- Kprep: decompose weights into bf16 hi/lo ----------------
__global__ void k_prep(const float* __restrict__ w1, const float* __restrict__ w2,
                       u16* __restrict__ w1h, u16* __restrict__ w1l,
                       u16* __restrict__ w2h, u16* __restrict__ w2l) {
    int i = blockIdx.x * 256 + threadIdx.x;
    if (i < HID_ * C_) {
        float v = w1[i];
        u16 h = f2bf(v);
        w1h[i] = h;
        w1l[i] = f2bf(v - bf2f(h));
    } else {
        int j = i - HID_ * C_;
        if (j < HID_ * HID_) {
            float v = w2[j];
            u16 h = f2bf(v);
            w2h[j] = h;
            w2l[j] = f2bf(v - bf2f(h));
        }
    }
}

// ---------------- K1: conv1 via bf16x2 MFMA ----------------
__global__ __launch_bounds__(256) void k1_conv1(const float* __restrict__ x,
                                                const u16* __restrict__ w1h,
                                                const u16* __restrict__ w1l,
                                                const float* __restrict__ b1,
                                                u16* __restrict__ h1h,
                                                u16* __restrict__ h1l) {
    __shared__ __align__(16) u16 Ah[128 * LDA];
    __shared__ __align__(16) u16 Al[128 * LDA];
    __shared__ __align__(16) u16 Bh[128 * LDA];
    __shared__ __align__(16) u16 Bl[128 * LDA];
    const int t = threadIdx.x;
    const int l = t & 63, wv = t >> 6;
    const int row = l & 15, q = l >> 4;
    const int pbase = blockIdx.x * 128, obase = blockIdx.y * 128, b = blockIdx.z;
    const int mwave = (wv & 1) * 64, nwave = (wv >> 1) * 64;
    const float* xb = x + (size_t)b * C_ * PIX_ + pbase;

    f32x4 acc[4][4];
#pragma unroll
    for (int i = 0; i < 4; i++)
#pragma unroll
        for (int j = 0; j < 4; j++) acc[i][j] = (f32x4){0.f, 0.f, 0.f, 0.f};

    for (int k0 = 0; k0 < C_; k0 += 32) {
        {
            int o = t >> 1, hf = t & 1;
            const float4* sh = (const float4*)&w1h[(size_t)(obase + o) * C_ + k0 + hf * 16];
            const float4* sl = (const float4*)&w1l[(size_t)(obase + o) * C_ + k0 + hf * 16];
            float4 vh0 = sh[0], vh1 = sh[1];
            float4 vl0 = sl[0], vl1 = sl[1];
            *(float4*)&Ah[o * LDA + hf * 16] = vh0;
            *(float4*)&Ah[o * LDA + hf * 16 + 8] = vh1;
            *(float4*)&Al[o * LDA + hf * 16] = vl0;
            *(float4*)&Al[o * LDA + hf * 16 + 8] = vl1;
        }
        {
            int cp = t & 15, pg = t >> 4;
            int c = k0 + cp * 2;
            float4 a0 = *(const float4*)&xb[(size_t)c * PIX_ + pg * 8];
            float4 a1 = *(const float4*)&xb[(size_t)c * PIX_ + pg * 8 + 4];
            float4 c0v = *(const float4*)&xb[(size_t)(c + 1) * PIX_ + pg * 8];
            float4 c1v = *(const float4*)&xb[(size_t)(c + 1) * PIX_ + pg * 8 + 4];
            float va[8] = {a0.x, a0.y, a0.z, a0.w, a1.x, a1.y, a1.z, a1.w};
            float vb[8] = {c0v.x, c0v.y, c0v.z, c0v.w, c1v.x, c1v.y, c1v.z, c1v.w};
#pragma unroll
            for (int j = 0; j < 8; j++) {
                u16 h0 = f2bf(va[j]), h1v = f2bf(vb[j]);
                u16 l0 = f2bf(va[j] - bf2f(h0)), l1 = f2bf(vb[j] - bf2f(h1v));
                *(unsigned int*)&Bh[(pg * 8 + j) * LDA + cp * 2] =
                    (unsigned int)h0 | ((unsigned int)h1v << 16);
                *(unsigned int*)&Bl[(pg * 8 + j) * LDA + cp * 2] =
                    (unsigned int)l0 | ((unsigned int)l1 << 16);
            }
        }
        __syncthreads();

        bf16x8 afh[4], afl[4], bfh[4], bfl[4];
#pragma unroll
        for (int mf = 0; mf < 4; mf++) {
            afh[mf] = *(const bf16x8*)&Ah[(mwave + mf * 16 + row) * LDA + q * 8];
            afl[mf] = *(const bf16x8*)&Al[(mwave + mf * 16 + row) * LDA + q * 8];
        }
#pragma unroll
        for (int nf = 0; nf < 4; nf++) {
            bfh[nf] = *(const bf16x8*)&Bh[(nwave + nf * 16 + row) * LDA + q * 8];
            bfl[nf] = *(const bf16x8*)&Bl[(nwave + nf * 16 + row) * LDA + q * 8];
        }
#pragma unroll
        for (int mf = 0; mf < 4; mf++)
#pragma unroll
            for (int nf = 0; nf < 4; nf++) {
                acc[mf][nf] = __builtin_amdgcn_mfma_f32_16x16x32_bf16(afh[mf], bfh[nf], acc[mf][nf], 0, 0, 0);
                acc[mf][nf] = __builtin_amdgcn_mfma_f32_16x16x32_bf16(afh[mf], bfl[nf], acc[mf][nf], 0, 0, 0);
                acc[mf][nf] = __builtin_amdgcn_mfma_f32_16x16x32_bf16(afl[mf], bfh[nf], acc[mf][nf], 0, 0, 0);
            }
        __syncthreads();
    }

#pragma unroll
    for (int mf = 0; mf < 4; mf++) {
        int o = obase + mwave + mf * 16 + q * 4;
        float bias[4];
#pragma unroll
        for (int r = 0; r < 4; r++) bias[r] = b1[o + r];
#pragma unroll
        for (int nf = 0; nf < 4; nf++) {
            int p = pbase + nwave + nf * 16 + row;
            u16 hh[4], ll[4];
#pragma unroll
            for (int r = 0; r < 4; r++) {
                float v = fmaxf(acc[mf][nf][r] + bias[r], 0.f);
                u16 h = f2bf(v);
                hh[r] = h;
                ll[r] = f2bf(v - bf2f(h));
            }
            size_t base = ((size_t)b * PIX_ + p) * HID_ + o;
            *(unsigned long long*)&h1h[base] =
                (unsigned long long)hh[0] | ((unsigned long long)hh[1] << 16) |
                ((unsigned long long)hh[2] << 32) | ((unsigned long long)hh[3] << 48);
            *(unsigned long long*)&h1l[base] =
                (unsigned long long)ll[0] | ((unsigned long long)ll[1] << 16) |
                ((unsigned long long)ll[2] << 32) | ((unsigned long long)ll[3] << 48);
        }
    }
}

// ---------------- K2: conv2 via bf16x2 MFMA + fused score reductions ----------------
__global__ __launch_bounds__(256) void k2_conv2_scores(
    const u16* __restrict__ h1h, const u16* __restrict__ h1l,
    const u16* __restrict__ w2h, const u16* __restrict__ w2l,
    const float* __restrict__ b2, const float* __restrict__ w_row,
    const float* __restrict__ w_col, float* __restrict__ row_s,
    float* __restrict__ col_s) {
    __shared__ __align__(16) u16 Ah[128 * LDA];
    __shared__ __align__(16) u16 Al[128 * LDA];
    __shared__ __align__(16) u16 Bh[128 * LDA];
    __shared__ __align__(16) u16 Bl[128 * LDA];
    __shared__ float col_red[64];
    __shared__ float row_red[2];
    const int t = threadIdx.x;
    const int l = t & 63, wv = t >> 6;
    const int row = l & 15, q = l >> 4;
    const int pbase = blockIdx.x * 128, obase = blockIdx.y * 128, b = blockIdx.z;
    const int mwave = (wv & 1) * 64, nwave = (wv >> 1) * 64;

    if (t < 64) col_red[t] = 0.f;
    if (t < 2) row_red[t] = 0.f;

    f32x4 acc[4][4];
#pragma unroll
    for (int i = 0; i < 4; i++)
#pragma unroll
        for (int j = 0; j < 4; j++) acc[i][j] = (f32x4){0.f, 0.f, 0.f, 0.f};

    for (int k0 = 0; k0 < HID_; k0 += 32) {
        {
            int o = t >> 1, hf = t & 1;
            const float4* sh = (const float4*)&w2h[(size_t)(obase + o) * HID_ + k0 + hf * 16];
            const float4* sl = (const float4*)&w2l[(size_t)(obase + o) * HID_ + k0 + hf * 16];
            float4 vh0 = sh[0], vh1 = sh[1];
            float4 vl0 = sl[0], vl1 = sl[1];
            *(float4*)&Ah[o * LDA + hf * 16] = vh0;
            *(float4*)&Ah[o * LDA + hf * 16 + 8] = vh1;
            *(float4*)&Al[o * LDA + hf * 16] = vl0;
            *(float4*)&Al[o * LDA + hf * 16 + 8] = vl1;
        }
        {
            int p = t >> 1, hf = t & 1;
            size_t base = ((size_t)b * PIX_ + pbase + p) * HID_ + k0 + hf * 16;
            const float4* sh = (const float4*)&h1h[base];
            const float4* sl = (const float4*)&h1l[base];
            float4 vh0 = sh[0], vh1 = sh[1];
            float4 vl0 = sl[0], vl1 = sl[1];
            *(float4*)&Bh[p * LDA + hf * 16] = vh0;
            *(float4*)&Bh[p * LDA + hf * 16 + 8] = vh1;
            *(float4*)&Bl[p * LDA + hf * 16] = vl0;
            *(float4*)&Bl[p * LDA + hf * 16 + 8] = vl1;
        }
        __syncthreads();

        bf16x8 afh[4], afl[4], bfh[4], bfl[4];
#pragma unroll
        for (int mf = 0; mf < 4; mf++) {
            afh[mf] = *(const bf16x8*)&Ah[(mwave + mf * 16 + row) * LDA + q * 8];
            afl[mf] = *(const bf16x8*)&Al[(mwave + mf * 16 + row) * LDA + q * 8];
        }
#pragma unroll
        for (int nf = 0; nf < 4; nf++) {
            bfh[nf] = *(const bf16x8*)&Bh[(nwave + nf * 16 + row) * LDA + q * 8];
            bfl[nf] = *(const bf16x8*)&Bl[(nwave + nf * 16 + row) * LDA + q * 8];
        }
#pragma unroll
        for (int mf = 0; mf < 4; mf++)
#pragma unroll
            for (int nf = 0; nf < 4; nf++) {
                acc[mf][nf] = __builtin_amdgcn_mfma_f32_16x16x32_bf16(afh[mf], bfh[nf], acc[mf][nf], 0, 0, 0);
                acc[mf][nf] = __builtin_amdgcn_mfma_f32_16x16x32_bf16(afh[mf], bfl[nf], acc[mf][nf], 0, 0, 0);
                acc[mf][nf] = __builtin_amdgcn_mfma_f32_16x16x32_bf16(afl[mf], bfh[nf], acc[mf][nf], 0, 0, 0);
            }
        __syncthreads();
    }

    const int h0 = pbase >> 6;
    const int h = h0 + (wv >> 1);
    float rpart = 0.f;
    float cpart[4] = {0.f, 0.f, 0.f, 0.f};
#pragma unroll
    for (int mf = 0; mf < 4; mf++) {
        int o = obase + mwave + mf * 16 + q * 4;
#pragma unroll
        for (int r = 0; r < 4; r++) {
            float bias = b2[o + r];
            float wcv = w_col[(o + r) * N_ + h];
#pragma unroll
            for (int nf = 0; nf < 4; nf++) {
                int w = nf * 16 + row;
                float v = fmaxf(acc[mf][nf][r] + bias, 0.f);
                rpart += v * w_row[(o + r) * N_ + w];
                cpart[nf] += v * wcv;
            }
        }
    }
    __syncthreads();
#pragma unroll
    for (int off = 32; off; off >>= 1) rpart += __shfl_xor(rpart, off, 64);
    if (l == 0) atomicAdd(&row_red[wv >> 1], rpart);
#pragma unroll
    for (int nf = 0; nf < 4; nf++) {
        float cp = cpart[nf];
        cp += __shfl_xor(cp, 16, 64);
        cp += __shfl_xor(cp, 32, 64);
        if (l < 16) atomicAdd(&col_red[nf * 16 + l], cp);
    }
    __syncthreads();
    if (t < 64) atomicAdd(&col_s[b * N_ + t], col_red[t]);
    if (t < 2) atomicAdd(&row_s[b * N_ + h0 + t], row_red[t]);
}

// ---------------- K4: diff bitonic sort -> P as bf16 hi/lo ----------------
__global__ __launch_bounds__(256) void k4_diffsort(const float* __restrict__ row_s,
                                                   const float* __restrict__ col_s,
                                                   u16* __restrict__ prow_h, u16* __restrict__ prow_l,
                                                   u16* __restrict__ pcol_h, u16* __restrict__ pcol_l) {
    __shared__ float Ps[64 * 65];
    __shared__ float xs[64];
    __shared__ float als[32];
    const int t = threadIdx.x;
    const int which = blockIdx.x & 1;
    const int b = blockIdx.x >> 1;
    const float* sc = which ? col_s : row_s;
    u16* Ph = which ? pcol_h : prow_h;
    u16* Pl = which ? pcol_l : prow_l;

    if (t < 64) xs[t] = sc[b * 64 + t];
#pragma unroll
    for (int k = 0; k < 16; k++) {
        int idx = t + k * 256;
        int i = idx >> 6, j = idx & 63;
        Ps[i * 65 + j] = (i == j) ? 1.f : 0.f;
    }
    __syncthreads();

    const int r = t & 63, pg = t >> 6;
    for (int bl = 0; bl < 6; bl++) {
        for (int ly = 0; ly <= bl; ly++) {
            int sh = bl - ly;
            int m = 1 << sh;
            if (t < 32) {
                int i = (t >> sh) << (sh + 1);
                int j = t & (m - 1);
                int ix = i + j;
                int a = ix, bi = ix + m;
                if ((ix >> (bl + 1)) & 1) { int tmp = a; a = bi; bi = tmp; }
                float xa = xs[a], xbv = xs[bi];
                float al = atanf((xbv - xa) * STEEP) * INV_PI + 0.5f;
                als[t] = al;
                xs[a] = al * xa + (1.f - al) * xbv;
                xs[bi] = (1.f - al) * xa + al * xbv;
            }
            __syncthreads();
#pragma unroll
            for (int pi = 0; pi < 8; pi++) {
                int p = pg * 8 + pi;
                int i = (p >> sh) << (sh + 1);
                int j = p & (m - 1);
                int ix = i + j;
                int a = ix, bi = ix + m;
                if ((ix >> (bl + 1)) & 1) { int tmp = a; a = bi; bi = tmp; }
                float al = als[p];
                float Pa = Ps[r * 65 + a], Pb = Ps[r * 65 + bi];
                Ps[r * 65 + a] = al * Pa + (1.f - al) * Pb;
                Ps[r * 65 + bi] = (1.f - al) * Pa + al * Pb;
            }
            __syncthreads();
        }
    }
#pragma unroll
    for (int k = 0; k < 16; k++) {
        int idx = t + k * 256;
        int i = idx >> 6, j = idx & 63;
        float v = Ps[i * 65 + j];
        u16 h = f2bf(v);
        Ph[b * 4096 + idx] = h;
        Pl[b * 4096 + idx] = f2bf(v - bf2f(h));
    }
}

// ---------------- K5: fused double permutation via MFMA ----------------
// Z = Pcol @ x^T  (Z[i][m] = sum_j Pcol[i][j] x[m][j]), out = Z @ Prow^T.
// No transposes needed: all operands are k-contiguous in their natural layouts.
__global__ __launch_bounds__(256) void k5_permute(const float* __restrict__ x,
                                                  const u16* __restrict__ pcol_h,
                                                  const u16* __restrict__ pcol_l,
                                                  const u16* __restrict__ prow_h,
                                                  const u16* __restrict__ prow_l,
                                                  float* __restrict__ out) {
    __shared__ __align__(16) u16 Xh[64 * LDX];
    __shared__ __align__(16) u16 Xl[64 * LDX];
    __shared__ __align__(16) u16 Zh[64 * LDX];
    __shared__ __align__(16) u16 Zl[64 * LDX];
    const int t = threadIdx.x;
    const int l = t & 63, w = t >> 6;
    const int col = l & 15, q = l >> 4;
    const int b = blockIdx.y;
    const int cbase = blockIdx.x * 4;
    const int i0 = w * 16;

    const u16* pch = pcol_h + (size_t)b * 4096;
    const u16* pcl = pcol_l + (size_t)b * 4096;
    const u16* prh = prow_h + (size_t)b * 4096;
    const u16* prl = prow_l + (size_t)b * 4096;

    // persistent stage-1 A fragments (Pcol rows i0..i0+15)
    bf16x8 pcA_h[2], pcA_l[2];
#pragma unroll
    for (int ks = 0; ks < 2; ks++) {
        pcA_h[ks] = *(const bf16x8*)&pch[(i0 + col) * 64 + q * 8 + ks * 32];
        pcA_l[ks] = *(const bf16x8*)&pcl[(i0 + col) * 64 + q * 8 + ks * 32];
    }

    for (int ci = 0; ci < 4; ci++) {
        const int c = cbase + ci;
        const float* xc = x + ((size_t)b * C_ + c) * PIX_;
        // stage x -> LDS (hi/lo bf16, row-major [m][j])
#pragma unroll
        for (int k = 0; k < 4; k++) {
            int f = t + k * 256;            // float4 index 0..1023
            int rw = f >> 4, c4 = f & 15;
            float4 v = *(const float4*)&xc[f * 4];
            u16 h0 = f2bf(v.x), h1 = f2bf(v.y), h2 = f2bf(v.z), h3 = f2bf(v.w);
            ushort4 hv = {h0, h1, h2, h3};
            ushort4 lv = {f2bf(v.x - bf2f(h0)), f2bf(v.y - bf2f(h1)),
                          f2bf(v.z - bf2f(h2)), f2bf(v.w - bf2f(h3))};
            *(ushort4*)&Xh[rw * LDX + c4 * 4] = hv;
            *(ushort4*)&Xl[rw * LDX + c4 * 4] = lv;
        }
        __syncthreads();

        // stage 1: wave w computes Z rows i0..i0+15 (all 64 m-cols)
        f32x4 acc[4];
#pragma unroll
        for (int nt = 0; nt < 4; nt++) acc[nt] = (f32x4){0.f, 0.f, 0.f, 0.f};
#pragma unroll
        for (int ks = 0; ks < 2; ks++) {
            bf16x8 ah = pcA_h[ks], al_ = pcA_l[ks];
#pragma unroll
            for (int nt = 0; nt < 4; nt++) {
                bf16x8 bh = *(const bf16x8*)&Xh[(nt * 16 + col) * LDX + q * 8 + ks * 32];
                bf16x8 bl = *(const bf16x8*)&Xl[(nt * 16 + col) * LDX + q * 8 + ks * 32];
                acc[nt] = __builtin_amdgcn_mfma_f32_16x16x32_bf16(ah, bh, acc[nt], 0, 0, 0);
                acc[nt] = __builtin_amdgcn_mfma_f32_16x16x32_bf16(ah, bl, acc[nt], 0, 0, 0);
                acc[nt] = __builtin_amdgcn_mfma_f32_16x16x32_bf16(al_, bh, acc[nt], 0, 0, 0);
            }
        }
        // write Z strip (wave-private rows; no block barrier needed)
#pragma unroll
        for (int nt = 0; nt < 4; nt++)
#pragma unroll
            for (int r = 0; r < 4; r++) {
                float v = acc[nt][r];
                u16 h = f2bf(v);
                int rw = i0 + q * 4 + r;
                Zh[rw * LDX + nt * 16 + col] = h;
                Zl[rw * LDX + nt * 16 + col] = f2bf(v - bf2f(h));
            }

        // stage 2: out rows i0..i0+15 = Z_strip @ Prow^T
        f32x4 acc2[4];
#pragma unroll
        for (int nt = 0; nt < 4; nt++) acc2[nt] = (f32x4){0.f, 0.f, 0.f, 0.f};
#pragma unroll
        for (int ks = 0; ks < 2; ks++) {
            bf16x8 ah = *(const bf16x8*)&Zh[(i0 + col) * LDX + q * 8 + ks * 32];
            bf16x8 al_ = *(const bf16x8*)&Zl[(i0 + col) * LDX + q * 8 + ks * 32];
#pragma unroll
            for (int nt = 0; nt < 4; nt++) {
                bf16x8 bh = *(const bf16x8*)&prh[(nt * 16 + col) * 64 + q * 8 + ks * 32];
                bf16x8 bl = *(const bf16x8*)&prl[(nt * 16 + col) * 64 + q * 8 + ks * 32];
                acc2[nt] = __builtin_amdgcn_mfma_f32_16x16x32_bf16(ah, bh, acc2[nt], 0, 0, 0);
                acc2[nt] = __builtin_amdgcn_mfma_f32_16x16x32_bf16(ah, bl, acc2[nt], 0, 0, 0);
                acc2[nt] = __builtin_amdgcn_mfma_f32_16x16x32_bf16(al_, bh, acc2[nt], 0, 0, 0);
            }
        }
        float* oc = out + ((size_t)b * C_ + c) * PIX_;
#pragma unroll
        for (int nt = 0; nt < 4; nt++)
#pragma unroll
            for (int r = 0; r < 4; r++)
                oc[(i0 + q * 4 + r) * 64 + nt * 16 + col] = acc2[nt][r];
        __syncthreads();
    }
}

extern "C" void kernel_launch(void* const* d_in, const int* in_sizes, int n_in,
                              void* d_out, int out_size, void* d_ws, size_t ws_size,
                              hipStream_t stream) {
    const float* x = (const float*)d_in[0];
    const float* w1 = (const float*)d_in[1];
    const float* b1 = (const float*)d_in[2];
    const float* w2 = (const float*)d_in[3];
    const float* b2 = (const float*)d_in[4];
    const float* w_row = (const float*)d_in[5];
    const float* b_row = (const float*)d_in[6];
    const float* w_col = (const float*)d_in[7];
    const float* b_col = (const float*)d_in[8];
    float* out = (float*)d_out;

    char* ws = (char*)d_ws;
    u16* h1h = (u16*)(ws);                               //  67108864 B
    u16* h1l = (u16*)(ws + 67108864);                    //  67108864 B
    u16* w1h = (u16*)(ws + 134217728);                   //  65536 B
    u16* w1l = (u16*)(ws + 134283264);                   //  65536 B
    u16* w2h = (u16*)(ws + 134348800);                   //  131072 B
    u16* w2l = (u16*)(ws + 134479872);                   //  131072 B
    float* row_s = (float*)(ws + 134610944);             //  8192 B
    float* col_s = (float*)(ws + 134619136);             //  8192 B
    u16* prow_h = (u16*)(ws + 134627328);                //  262144 B
    u16* prow_l = (u16*)(ws + 134889472);                //  262144 B
    u16* pcol_h = (u16*)(ws + 135151616);                //  262144 B
    u16* pcol_l = (u16*)(ws + 135413760);                //  262144 B

    hipLaunchKernelGGL(k0_init, dim3(16), dim3(256), 0, stream, row_s, col_s, b_row, b_col);
    hipLaunchKernelGGL(k_prep, dim3(384), dim3(256), 0, stream, w1, w2, w1h, w1l, w2h, w2l);
    hipLaunchKernelGGL(k1_conv1, dim3(32, 2, 32), dim3(256), 0, stream, x, w1h, w1l, b1, h1h, h1l);
    hipLaunchKernelGGL(k2_conv2_scores, dim3(32, 2, 32), dim3(256), 0, stream,
                       h1h, h1l, w2h, w2l, b2, w_row, w_col, row_s, col_s);
    hipLaunchKernelGGL(k4_diffsort, dim3(64), dim3(256), 0, stream,
                       row_s, col_s, prow_h, prow_l, pcol_h, pcol_l);
    hipLaunchKernelGGL(k5_permute, dim3(32, 32), dim3(256), 0, stream,
                       x, pcol_h, pcol_l, prow_h, prow_l, out);
}

// Round 4
// 292.475 us; speedup vs baseline: 1.9211x; 1.0948x over previous
//
#include <hip/hip_runtime.h>
#include <math.h>

#define B_    32
#define C_    128
#define N_    64
#define HID_  256
#define PIX_  4096
#define STEEP 50.0f
#define INV_PI 0.318309886183790671f
#define LDA   40   // LDS row pitch in bf16 for 32-wide K tiles
#define LDH   272  // LDS row pitch in bf16 for h1 tile rows (256 data + 16 pad)
#define LDX   72   // LDS row pitch in bf16 for 64-wide rows (k5)

typedef unsigned short u16;
typedef __attribute__((ext_vector_type(8))) short bf16x8;
typedef __attribute__((ext_vector_type(4))) float f32x4;

__device__ __forceinline__ u16 f2bf(float f) {
    unsigned int u = __builtin_bit_cast(unsigned int, f);
    unsigned int r = (u + 0x7FFFu + ((u >> 16) & 1u)) >> 16;
    return (u16)r;
}
__device__ __forceinline__ float bf2f(u16 h) {
    unsigned int u = ((unsigned int)h) << 16;
    return __builtin_bit_cast(float, u);
}

// ---------------- K0: init col score buffer with bias ----------------
__global__ void k0_init(float* __restrict__ col_s, const float* __restrict__ b_col) {
    int i = blockIdx.x * 256 + threadIdx.x;
    if (i < B_ * N_) col_s[i] = b_col[0];
}

// ---------------- Kprep: decompose weights into bf16 hi/lo ----------------
__global__ void k_prep(const float* __restrict__ w1, const float* __restrict__ w2,
                       u16* __restrict__ w1h, u16* __restrict__ w1l,
                       u16* __restrict__ w2h, u16* __restrict__ w2l) {
    int i = blockIdx.x * 256 + threadIdx.x;
    if (i < HID_ * C_) {
        float v = w1[i];
        u16 h = f2bf(v);
        w1h[i] = h;
        w1l[i] = f2bf(v - bf2f(h));
    } else {
        int j = i - HID_ * C_;
        if (j < HID_ * HID_) {
            float v = w2[j];
            u16 h = f2bf(v);
            w2h[j] = h;
            w2l[j] = f2bf(v - bf2f(h));
        }
    }
}

// ---------------- K12: fused conv1+conv2+scores ----------------
// Block: batch b = blockIdx.y, image row h = blockIdx.x (64 pixels).
// conv1: h1[p][c2] (c2=256) kept in LDS bf16 hi/lo; conv2 reads it as B-frags,
// w2 A-frags straight from global (L2-hot). Scores fused in epilogue.
__global__ __launch_bounds__(256) void k12_fused(
    const float* __restrict__ x,
    const u16* __restrict__ w1h, const u16* __restrict__ w1l,
    const float* __restrict__ b1,
    const u16* __restrict__ w2h, const u16* __restrict__ w2l,
    const float* __restrict__ b2, const float* __restrict__ w_row,
    const float* __restrict__ b_row, const float* __restrict__ w_col,
    float* __restrict__ row_s, float* __restrict__ col_s) {
    __shared__ __align__(16) u16 Lh1h[64 * LDH];   // 34816 B
    __shared__ __align__(16) u16 Lh1l[64 * LDH];   // 34816 B
    __shared__ __align__(16) u16 Bh[64 * LDA];     // 5120 B
    __shared__ __align__(16) u16 Bl[64 * LDA];     // 5120 B
    __shared__ float col_red[64];
    __shared__ float row_red;

    const int t = threadIdx.x;
    const int l = t & 63, w = t >> 6;
    const int col = l & 15, q = l >> 4;
    const int hrow = blockIdx.x;
    const int b = blockIdx.y;
    const int pbase = hrow * 64;
    const float* xb = x + (size_t)b * C_ * PIX_ + pbase;

    if (t < 64) col_red[t] = 0.f;
    if (t == 0) row_red = 0.f;

    // ---- conv1: acc[mf][nt] covers o=64w+16mf+.., p=16nt+.. ----
    f32x4 acc[4][4];
#pragma unroll
    for (int i = 0; i < 4; i++)
#pragma unroll
        for (int j = 0; j < 4; j++) acc[i][j] = (f32x4){0.f, 0.f, 0.f, 0.f};

    const int pt = t & 15, ct = t >> 4;   // staging roles: p-group, c-pair
    for (int kc = 0; kc < 4; kc++) {
        const int c0 = kc * 32;
        // stage x chunk [64 p][32 k] -> Bh/Bl (transpose + hi/lo split)
        {
            const float* r0 = &xb[(size_t)(c0 + 2 * ct) * PIX_ + pt * 4];
            const float* r1 = &xb[(size_t)(c0 + 2 * ct + 1) * PIX_ + pt * 4];
            float4 v0 = *(const float4*)r0;
            float4 v1 = *(const float4*)r1;
            float a0[4] = {v0.x, v0.y, v0.z, v0.w};
            float a1[4] = {v1.x, v1.y, v1.z, v1.w};
#pragma unroll
            for (int j = 0; j < 4; j++) {
                u16 h0 = f2bf(a0[j]), h1 = f2bf(a1[j]);
                u16 l0 = f2bf(a0[j] - bf2f(h0)), l1 = f2bf(a1[j] - bf2f(h1));
                *(unsigned int*)&Bh[(pt * 4 + j) * LDA + 2 * ct] =
                    (unsigned int)h0 | ((unsigned int)h1 << 16);
                *(unsigned int*)&Bl[(pt * 4 + j) * LDA + 2 * ct] =
                    (unsigned int)l0 | ((unsigned int)l1 << 16);
            }
        }
        __syncthreads();
        // A-frags direct from global (w1 L2-hot), B-frags from LDS
        bf16x8 ah[4], al_[4], bh[4], bl[4];
#pragma unroll
        for (int mf = 0; mf < 4; mf++) {
            size_t ro = (size_t)(64 * w + 16 * mf + col) * C_ + c0 + q * 8;
            ah[mf] = *(const bf16x8*)&w1h[ro];
            al_[mf] = *(const bf16x8*)&w1l[ro];
        }
#pragma unroll
        for (int nt = 0; nt < 4; nt++) {
            bh[nt] = *(const bf16x8*)&Bh[(nt * 16 + col) * LDA + q * 8];
            bl[nt] = *(const bf16x8*)&Bl[(nt * 16 + col) * LDA + q * 8];
        }
#pragma unroll
        for (int mf = 0; mf < 4; mf++)
#pragma unroll
            for (int nt = 0; nt < 4; nt++) {
                acc[mf][nt] = __builtin_amdgcn_mfma_f32_16x16x32_bf16(ah[mf], bh[nt], acc[mf][nt], 0, 0, 0);
                acc[mf][nt] = __builtin_amdgcn_mfma_f32_16x16x32_bf16(ah[mf], bl[nt], acc[mf][nt], 0, 0, 0);
                acc[mf][nt] = __builtin_amdgcn_mfma_f32_16x16x32_bf16(al_[mf], bh[nt], acc[mf][nt], 0, 0, 0);
            }
        __syncthreads();
    }

    // ---- conv1 epilogue: relu(acc+b1) -> Lh1 hi/lo at [p][o] ----
#pragma unroll
    for (int mf = 0; mf < 4; mf++) {
        int o = 64 * w + 16 * mf + q * 4;
        float bias[4];
#pragma unroll
        for (int r = 0; r < 4; r++) bias[r] = b1[o + r];
#pragma unroll
        for (int nt = 0; nt < 4; nt++) {
            int p = nt * 16 + col;
            u16 hh[4], ll[4];
#pragma unroll
            for (int r = 0; r < 4; r++) {
                float v = fmaxf(acc[mf][nt][r] + bias[r], 0.f);
                u16 h = f2bf(v);
                hh[r] = h;
                ll[r] = f2bf(v - bf2f(h));
            }
            *(unsigned long long*)&Lh1h[p * LDH + o] =
                (unsigned long long)hh[0] | ((unsigned long long)hh[1] << 16) |
                ((unsigned long long)hh[2] << 32) | ((unsigned long long)hh[3] << 48);
            *(unsigned long long*)&Lh1l[p * LDH + o] =
                (unsigned long long)ll[0] | ((unsigned long long)ll[1] << 16) |
                ((unsigned long long)ll[2] << 32) | ((unsigned long long)ll[3] << 48);
        }
    }
    __syncthreads();

    // ---- conv2: o2=64w+16mf+.., p=16nt+.., K=256 over h1 channels ----
    f32x4 acc2[4][4];
#pragma unroll
    for (int i = 0; i < 4; i++)
#pragma unroll
        for (int j = 0; j < 4; j++) acc2[i][j] = (f32x4){0.f, 0.f, 0.f, 0.f};

    for (int kc = 0; kc < 8; kc++) {
        const int k0 = kc * 32;
        bf16x8 ah[4], al_[4], bh[4], bl[4];
#pragma unroll
        for (int mf = 0; mf < 4; mf++) {
            size_t ro = (size_t)(64 * w + 16 * mf + col) * HID_ + k0 + q * 8;
            ah[mf] = *(const bf16x8*)&w2h[ro];
            al_[mf] = *(const bf16x8*)&w2l[ro];
        }
#pragma unroll
        for (int nt = 0; nt < 4; nt++) {
            bh[nt] = *(const bf16x8*)&Lh1h[(nt * 16 + col) * LDH + k0 + q * 8];
            bl[nt] = *(const bf16x8*)&Lh1l[(nt * 16 + col) * LDH + k0 + q * 8];
        }
#pragma unroll
        for (int mf = 0; mf < 4; mf++)
#pragma unroll
            for (int nt = 0; nt < 4; nt++) {
                acc2[mf][nt] = __builtin_amdgcn_mfma_f32_16x16x32_bf16(ah[mf], bh[nt], acc2[mf][nt], 0, 0, 0);
                acc2[mf][nt] = __builtin_amdgcn_mfma_f32_16x16x32_bf16(ah[mf], bl[nt], acc2[mf][nt], 0, 0, 0);
                acc2[mf][nt] = __builtin_amdgcn_mfma_f32_16x16x32_bf16(al_[mf], bh[nt], acc2[mf][nt], 0, 0, 0);
            }
    }

    // ---- score epilogue: h2 = relu(acc2+b2), reduce into row/col scores ----
    float rpart = 0.f;
    float cpart[4] = {0.f, 0.f, 0.f, 0.f};
#pragma unroll
    for (int mf = 0; mf < 4; mf++) {
        int o = 64 * w + 16 * mf + q * 4;
#pragma unroll
        for (int r = 0; r < 4; r++) {
            float bias = b2[o + r];
            float wcv = w_col[(o + r) * N_ + hrow];
#pragma unroll
            for (int nt = 0; nt < 4; nt++) {
                int wc = nt * 16 + col;
                float v = fmaxf(acc2[mf][nt][r] + bias, 0.f);
                rpart += v * w_row[(o + r) * N_ + wc];
                cpart[nt] += v * wcv;
            }
        }
    }
#pragma unroll
    for (int off = 32; off; off >>= 1) rpart += __shfl_xor(rpart, off, 64);
    if (l == 0) atomicAdd(&row_red, rpart);
#pragma unroll
    for (int nt = 0; nt < 4; nt++) {
        float cp = cpart[nt];
        cp += __shfl_xor(cp, 16, 64);
        cp += __shfl_xor(cp, 32, 64);
        if (l < 16) atomicAdd(&col_red[nt * 16 + l], cp);
    }
    __syncthreads();
    if (t < 64) atomicAdd(&col_s[b * N_ + t], col_red[t]);
    if (t == 0) row_s[b * N_ + hrow] = b_row[0] + row_red;
}

// ---------------- K4: diff bitonic sort -> P as bf16 hi/lo ----------------
__global__ __launch_bounds__(256) void k4_diffsort(const float* __restrict__ row_s,
                                                   const float* __restrict__ col_s,
                                                   u16* __restrict__ prow_h, u16* __restrict__ prow_l,
                                                   u16* __restrict__ pcol_h, u16* __restrict__ pcol_l) {
    __shared__ float Ps[64 * 65];
    __shared__ float xs[64];
    __shared__ float als[32];
    const int t = threadIdx.x;
    const int which = blockIdx.x & 1;
    const int b = blockIdx.x >> 1;
    const float* sc = which ? col_s : row_s;
    u16* Ph = which ? pcol_h : prow_h;
    u16* Pl = which ? pcol_l : prow_l;

    if (t < 64) xs[t] = sc[b * 64 + t];
#pragma unroll
    for (int k = 0; k < 16; k++) {
        int idx = t + k * 256;
        int i = idx >> 6, j = idx & 63;
        Ps[i * 65 + j] = (i == j) ? 1.f : 0.f;
    }
    __syncthreads();

    const int r = t & 63, pg = t >> 6;
    for (int bl = 0; bl < 6; bl++) {
        for (int ly = 0; ly <= bl; ly++) {
            int sh = bl - ly;
            int m = 1 << sh;
            if (t < 32) {
                int i = (t >> sh) << (sh + 1);
                int j = t & (m - 1);
                int ix = i + j;
                int a = ix, bi = ix + m;
                if ((ix >> (bl + 1)) & 1) { int tmp = a; a = bi; bi = tmp; }
                float xa = xs[a], xbv = xs[bi];
                float al = atanf((xbv - xa) * STEEP) * INV_PI + 0.5f;
                als[t] = al;
                xs[a] = al * xa + (1.f - al) * xbv;
                xs[bi] = (1.f - al) * xa + al * xbv;
            }
            __syncthreads();
#pragma unroll
            for (int pi = 0; pi < 8; pi++) {
                int p = pg * 8 + pi;
                int i = (p >> sh) << (sh + 1);
                int j = p & (m - 1);
                int ix = i + j;
                int a = ix, bi = ix + m;
                if ((ix >> (bl + 1)) & 1) { int tmp = a; a = bi; bi = tmp; }
                float al = als[p];
                float Pa = Ps[r * 65 + a], Pb = Ps[r * 65 + bi];
                Ps[r * 65 + a] = al * Pa + (1.f - al) * Pb;
                Ps[r * 65 + bi] = (1.f - al) * Pa + al * Pb;
            }
            __syncthreads();
        }
    }
#pragma unroll
    for (int k = 0; k < 16; k++) {
        int idx = t + k * 256;
        int i = idx >> 6, j = idx & 63;
        float v = Ps[i * 65 + j];
        u16 h = f2bf(v);
        Ph[b * 4096 + idx] = h;
        Pl[b * 4096 + idx] = f2bf(v - bf2f(h));
    }
}

// ---------------- K5: fused double permutation via MFMA ----------------
// Z = Pcol @ x^T, out = Z @ Prow^T (all operands naturally k-contiguous).
__global__ __launch_bounds__(256) void k5_permute(const float* __restrict__ x,
                                                  const u16* __restrict__ pcol_h,
                                                  const u16* __restrict__ pcol_l,
                                                  const u16* __restrict__ prow_h,
                                                  const u16* __restrict__ prow_l,
                                                  float* __restrict__ out) {
    __shared__ __align__(16) u16 Xh[64 * LDX];
    __shared__ __align__(16) u16 Xl[64 * LDX];
    __shared__ __align__(16) u16 Zh[64 * LDX];
    __shared__ __align__(16) u16 Zl[64 * LDX];
    const int t = threadIdx.x;
    const int l = t & 63, w = t >> 6;
    const int col = l & 15, q = l >> 4;
    const int b = blockIdx.y;
    const int cbase = blockIdx.x * 4;
    const int i0 = w * 16;

    const u16* pch = pcol_h + (size_t)b * 4096;
    const u16* pcl = pcol_l + (size_t)b * 4096;
    const u16* prh = prow_h + (size_t)b * 4096;
    const u16* prl = prow_l + (size_t)b * 4096;

    bf16x8 pcA_h[2], pcA_l[2];
#pragma unroll
    for (int ks = 0; ks < 2; ks++) {
        pcA_h[ks] = *(const bf16x8*)&pch[(i0 + col) * 64 + q * 8 + ks * 32];
        pcA_l[ks] = *(const bf16x8*)&pcl[(i0 + col) * 64 + q * 8 + ks * 32];
    }

    for (int ci = 0; ci < 4; ci++) {
        const int c = cbase + ci;
        const float* xc = x + ((size_t)b * C_ + c) * PIX_;
#pragma unroll
        for (int k = 0; k < 4; k++) {
            int f = t + k * 256;
            int rw = f >> 4, c4 = f & 15;
            float4 v = *(const float4*)&xc[f * 4];
            u16 h0 = f2bf(v.x), h1 = f2bf(v.y), h2 = f2bf(v.z), h3 = f2bf(v.w);
            ushort4 hv = {h0, h1, h2, h3};
            ushort4 lv = {f2bf(v.x - bf2f(h0)), f2bf(v.y - bf2f(h1)),
                          f2bf(v.z - bf2f(h2)), f2bf(v.w - bf2f(h3))};
            *(ushort4*)&Xh[rw * LDX + c4 * 4] = hv;
            *(ushort4*)&Xl[rw * LDX + c4 * 4] = lv;
        }
        __syncthreads();

        f32x4 acc[4];
#pragma unroll
        for (int nt = 0; nt < 4; nt++) acc[nt] = (f32x4){0.f, 0.f, 0.f, 0.f};
#pragma unroll
        for (int ks = 0; ks < 2; ks++) {
            bf16x8 ah = pcA_h[ks], al_ = pcA_l[ks];
#pragma unroll
            for (int nt = 0; nt < 4; nt++) {
                bf16x8 bh = *(const bf16x8*)&Xh[(nt * 16 + col) * LDX + q * 8 + ks * 32];
                bf16x8 bl = *(const bf16x8*)&Xl[(nt * 16 + col) * LDX + q * 8 + ks * 32];
                acc[nt] = __builtin_amdgcn_mfma_f32_16x16x32_bf16(ah, bh, acc[nt], 0, 0, 0);
                acc[nt] = __builtin_amdgcn_mfma_f32_16x16x32_bf16(ah, bl, acc[nt], 0, 0, 0);
                acc[nt] = __builtin_amdgcn_mfma_f32_16x16x32_bf16(al_, bh, acc[nt], 0, 0, 0);
            }
        }
#pragma unroll
        for (int nt = 0; nt < 4; nt++)
#pragma unroll
            for (int r = 0; r < 4; r++) {
                float v = acc[nt][r];
                u16 h = f2bf(v);
                int rw = i0 + q * 4 + r;
                Zh[rw * LDX + nt * 16 + col] = h;
                Zl[rw * LDX + nt * 16 + col] = f2bf(v - bf2f(h));
            }

        f32x4 acc2[4];
#pragma unroll
        for (int nt = 0; nt < 4; nt++) acc2[nt] = (f32x4){0.f, 0.f, 0.f, 0.f};
#pragma unroll
        for (int ks = 0; ks < 2; ks++) {
            bf16x8 ah = *(const bf16x8*)&Zh[(i0 + col) * LDX + q * 8 + ks * 32];
            bf16x8 al_ = *(const bf16x8*)&Zl[(i0 + col) * LDX + q * 8 + ks * 32];
#pragma unroll
            for (int nt = 0; nt < 4; nt++) {
                bf16x8 bh = *(const bf16x8*)&prh[(nt * 16 + col) * 64 + q * 8 + ks * 32];
                bf16x8 bl = *(const bf16x8*)&prl[(nt * 16 + col) * 64 + q * 8 + ks * 32];
                acc2[nt] = __builtin_amdgcn_mfma_f32_16x16x32_bf16(ah, bh, acc2[nt], 0, 0, 0);
                acc2[nt] = __builtin_amdgcn_mfma_f32_16x16x32_bf16(ah, bl, acc2[nt], 0, 0, 0);
                acc2[nt] = __builtin_amdgcn_mfma_f32_16x16x32_bf16(al_, bh, acc2[nt], 0, 0, 0);
            }
        }
        float* oc = out + ((size_t)b * C_ + c) * PIX_;
#pragma unroll
        for (int nt = 0; nt < 4; nt++)
#pragma unroll
            for (int r = 0; r < 4; r++)
                oc[(i0 + q * 4 + r) * 64 + nt * 16 + col] = acc2[nt][r];
        __syncthreads();
    }
}

extern "C" void kernel_launch(void* const* d_in, const int* in_sizes, int n_in,
                              void* d_out, int out_size, void* d_ws, size_t ws_size,
                              hipStream_t stream) {
    const float* x = (const float*)d_in[0];
    const float* w1 = (const float*)d_in[1];
    const float* b1 = (const float*)d_in[2];
    const float* w2 = (const float*)d_in[3];
    const float* b2 = (const float*)d_in[4];
    const float* w_row = (const float*)d_in[5];
    const float* b_row = (const float*)d_in[6];
    const float* w_col = (const float*)d_in[7];
    const float* b_col = (const float*)d_in[8];
    float* out = (float*)d_out;

    char* ws = (char*)d_ws;
    u16* w1h = (u16*)(ws);                   //  65536 B
    u16* w1l = (u16*)(ws + 65536);           //  65536 B
    u16* w2h = (u16*)(ws + 131072);          //  131072 B
    u16* w2l = (u16*)(ws + 262144);          //  131072 B
    float* row_s = (float*)(ws + 393216);    //  8192 B
    float* col_s = (float*)(ws + 401408);    //  8192 B
    u16* prow_h = (u16*)(ws + 409600);       //  262144 B
    u16* prow_l = (u16*)(ws + 671744);       //  262144 B
    u16* pcol_h = (u16*)(ws + 933888);       //  262144 B
    u16* pcol_l = (u16*)(ws + 1196032);      //  262144 B

    hipLaunchKernelGGL(k0_init, dim3(8), dim3(256), 0, stream, col_s, b_col);
    hipLaunchKernelGGL(k_prep, dim3(384), dim3(256), 0, stream, w1, w2, w1h, w1l, w2h, w2l);
    hipLaunchKernelGGL(k12_fused, dim3(64, 32), dim3(256), 0, stream,
                       x, w1h, w1l, b1, w2h, w2l, b2, w_row, b_row, w_col, row_s, col_s);
    hipLaunchKernelGGL(k4_diffsort, dim3(64), dim3(256), 0, stream,
                       row_s, col_s, prow_h, prow_l, pcol_h, pcol_l);
    hipLaunchKernelGGL(k5_permute, dim3(32, 32), dim3(256), 0, stream,
                       x, pcol_h, pcol_l, prow_h, prow_l, out);
}

// Round 5
// 291.508 us; speedup vs baseline: 1.9275x; 1.0033x over previous
//
#include <hip/hip_runtime.h>
#include <math.h>

#define B_    32
#define C_    128
#define N_    64
#define HID_  256
#define PIX_  4096
#define STEEP 50.0f
#define INV_PI 0.318309886183790671f
#define LDH   272  // LDS row pitch (u16): 32 h1 chunks (256) + 16 pad; x tile time-shares cols 128..255
#define LDX   72   // k5 pitch

typedef unsigned short u16;
typedef __attribute__((ext_vector_type(8))) short bf16x8;
typedef __attribute__((ext_vector_type(4))) float f32x4;

__device__ __forceinline__ u16 f2bf(float f) {
    unsigned int u = __builtin_bit_cast(unsigned int, f);
    unsigned int r = (u + 0x7FFFu + ((u >> 16) & 1u)) >> 16;
    return (u16)r;
}
__device__ __forceinline__ float bf2f(u16 h) {
    unsigned int u = ((unsigned int)h) << 16;
    return __builtin_bit_cast(float, u);
}
// swizzled LDS indices (chunk = 8 u16 = 16 B, rotated by row for bank spread)
__device__ __forceinline__ int h1_idx(int p, int k) {
    return p * LDH + (((k >> 3) + (p & 7)) & 31) * 8 + (k & 7);
}
__device__ __forceinline__ int x_idx(int p, int k) {
    return p * LDH + 128 + (((k >> 3) + (p & 7)) & 15) * 8 + (k & 7);
}

// ---------------- K0: init col score buffer with bias ----------------
__global__ void k0_init(float* __restrict__ col_s, const float* __restrict__ b_col) {
    int i = blockIdx.x * 256 + threadIdx.x;
    if (i < B_ * N_) col_s[i] = b_col[0];
}

// ---------------- Kprep: decompose weights into bf16 hi/lo ----------------
__global__ void k_prep(const float* __restrict__ w1, const float* __restrict__ w2,
                       u16* __restrict__ w1h, u16* __restrict__ w1l,
                       u16* __restrict__ w2h, u16* __restrict__ w2l) {
    int i = blockIdx.x * 256 + threadIdx.x;
    if (i < HID_ * C_) {
        float v = w1[i];
        u16 h = f2bf(v);
        w1h[i] = h;
        w1l[i] = f2bf(v - bf2f(h));
    } else {
        int j = i - HID_ * C_;
        if (j < HID_ * HID_) {
            float v = w2[j];
            u16 h = f2bf(v);
            w2h[j] = h;
            w2l[j] = f2bf(v - bf2f(h));
        }
    }
}

// ---------------- K12: fused conv1+conv2+scores, pipelined ----------------
__global__ __launch_bounds__(256) void k12_fused(
    const float* __restrict__ x,
    const u16* __restrict__ w1h, const u16* __restrict__ w1l,
    const float* __restrict__ b1,
    const u16* __restrict__ w2h, const u16* __restrict__ w2l,
    const float* __restrict__ b2, const float* __restrict__ w_row,
    const float* __restrict__ b_row, const float* __restrict__ w_col,
    float* __restrict__ row_s, float* __restrict__ col_s) {
    __shared__ __align__(16) u16 Lh[64 * LDH];   // 34816 B (h1 hi / x hi staging)
    __shared__ __align__(16) u16 Ll[64 * LDH];   // 34816 B (h1 lo / x lo staging)
    __shared__ float col_red[64];
    __shared__ float row_red;

    const int t = threadIdx.x;
    const int l = t & 63, w = t >> 6;
    const int col = l & 15, q = l >> 4;
    const int hrow = blockIdx.x;
    const int b = blockIdx.y;
    const float* xb = x + (size_t)b * C_ * PIX_ + hrow * 64;

    if (t < 64) col_red[t] = 0.f;
    if (t == 0) row_red = 0.f;

    // ---- stage FULL x tile [64 p][128 c] -> swizzled cols 128..255 (one barrier) ----
    {
        const int pt = t & 15, ct = t >> 4;      // ct 0..15
#pragma unroll
        for (int cc = 0; cc < 4; cc++) {
            const int c = cc * 32 + 2 * ct;
            float4 v0 = *(const float4*)&xb[(size_t)c * PIX_ + pt * 4];
            float4 v1 = *(const float4*)&xb[(size_t)(c + 1) * PIX_ + pt * 4];
            float a0[4] = {v0.x, v0.y, v0.z, v0.w};
            float a1[4] = {v1.x, v1.y, v1.z, v1.w};
#pragma unroll
            for (int j = 0; j < 4; j++) {
                int p = pt * 4 + j;
                u16 h0 = f2bf(a0[j]), h1v = f2bf(a1[j]);
                u16 l0 = f2bf(a0[j] - bf2f(h0)), l1 = f2bf(a1[j] - bf2f(h1v));
                int idx = x_idx(p, c);
                *(unsigned int*)&Lh[idx] = (unsigned int)h0 | ((unsigned int)h1v << 16);
                *(unsigned int*)&Ll[idx] = (unsigned int)l0 | ((unsigned int)l1 << 16);
            }
        }
    }
    __syncthreads();

    // ---- conv1: 192 MFMAs/wave, pipelined A (global) + B (LDS) ----
    f32x4 acc[4][4];
#pragma unroll
    for (int i = 0; i < 4; i++)
#pragma unroll
        for (int j = 0; j < 4; j++) acc[i][j] = (f32x4){0.f, 0.f, 0.f, 0.f};

    bf16x8 ah[4], al_[4];
#pragma unroll
    for (int mf = 0; mf < 4; mf++) {
        size_t ro = (size_t)(64 * w + 16 * mf + col) * C_ + q * 8;
        ah[mf] = *(const bf16x8*)&w1h[ro];
        al_[mf] = *(const bf16x8*)&w1l[ro];
    }
#pragma unroll
    for (int kc = 0; kc < 4; kc++) {
        bf16x8 bh[4], bl[4];
#pragma unroll
        for (int nt = 0; nt < 4; nt++) {
            int idx = x_idx(nt * 16 + col, kc * 32 + q * 8);
            bh[nt] = *(const bf16x8*)&Lh[idx];
            bl[nt] = *(const bf16x8*)&Ll[idx];
        }
        bf16x8 ahn[4], aln[4];
        const int kn = (kc + 1) & 3;
#pragma unroll
        for (int mf = 0; mf < 4; mf++) {
            size_t ro = (size_t)(64 * w + 16 * mf + col) * C_ + kn * 32 + q * 8;
            ahn[mf] = *(const bf16x8*)&w1h[ro];
            aln[mf] = *(const bf16x8*)&w1l[ro];
        }
#pragma unroll
        for (int mf = 0; mf < 4; mf++)
#pragma unroll
            for (int nt = 0; nt < 4; nt++) {
                acc[mf][nt] = __builtin_amdgcn_mfma_f32_16x16x32_bf16(ah[mf], bh[nt], acc[mf][nt], 0, 0, 0);
                acc[mf][nt] = __builtin_amdgcn_mfma_f32_16x16x32_bf16(ah[mf], bl[nt], acc[mf][nt], 0, 0, 0);
                acc[mf][nt] = __builtin_amdgcn_mfma_f32_16x16x32_bf16(al_[mf], bh[nt], acc[mf][nt], 0, 0, 0);
            }
#pragma unroll
        for (int mf = 0; mf < 4; mf++) { ah[mf] = ahn[mf]; al_[mf] = aln[mf]; }
    }

    // prefetch conv2's first A-frags before the barrier
    bf16x8 ah2[4], al2[4];
#pragma unroll
    for (int mf = 0; mf < 4; mf++) {
        size_t ro = (size_t)(64 * w + 16 * mf + col) * HID_ + q * 8;
        ah2[mf] = *(const bf16x8*)&w2h[ro];
        al2[mf] = *(const bf16x8*)&w2l[ro];
    }
    __syncthreads();   // all x-frag reads done; rows can be overwritten with h1

    // ---- conv1 epilogue: relu(acc+b1) -> swizzled h1 hi/lo ----
#pragma unroll
    for (int mf = 0; mf < 4; mf++) {
        int o = 64 * w + 16 * mf + q * 4;
        float bias[4];
#pragma unroll
        for (int r = 0; r < 4; r++) bias[r] = b1[o + r];
#pragma unroll
        for (int nt = 0; nt < 4; nt++) {
            int p = nt * 16 + col;
            u16 hh[4], ll[4];
#pragma unroll
            for (int r = 0; r < 4; r++) {
                float v = fmaxf(acc[mf][nt][r] + bias[r], 0.f);
                u16 h = f2bf(v);
                hh[r] = h;
                ll[r] = f2bf(v - bf2f(h));
            }
            int idx = h1_idx(p, o);
            *(unsigned long long*)&Lh[idx] =
                (unsigned long long)hh[0] | ((unsigned long long)hh[1] << 16) |
                ((unsigned long long)hh[2] << 32) | ((unsigned long long)hh[3] << 48);
            *(unsigned long long*)&Ll[idx] =
                (unsigned long long)ll[0] | ((unsigned long long)ll[1] << 16) |
                ((unsigned long long)ll[2] << 32) | ((unsigned long long)ll[3] << 48);
        }
    }
    __syncthreads();

    // ---- conv2: 384 MFMAs/wave, pipelined ----
    f32x4 acc2[4][4];
#pragma unroll
    for (int i = 0; i < 4; i++)
#pragma unroll
        for (int j = 0; j < 4; j++) acc2[i][j] = (f32x4){0.f, 0.f, 0.f, 0.f};

#pragma unroll
    for (int kc = 0; kc < 8; kc++) {
        bf16x8 bh[4], bl[4];
#pragma unroll
        for (int nt = 0; nt < 4; nt++) {
            int idx = h1_idx(nt * 16 + col, kc * 32 + q * 8);
            bh[nt] = *(const bf16x8*)&Lh[idx];
            bl[nt] = *(const bf16x8*)&Ll[idx];
        }
        bf16x8 ahn[4], aln[4];
        const int kn = (kc + 1) & 7;
#pragma unroll
        for (int mf = 0; mf < 4; mf++) {
            size_t ro = (size_t)(64 * w + 16 * mf + col) * HID_ + kn * 32 + q * 8;
            ahn[mf] = *(const bf16x8*)&w2h[ro];
            aln[mf] = *(const bf16x8*)&w2l[ro];
        }
#pragma unroll
        for (int mf = 0; mf < 4; mf++)
#pragma unroll
            for (int nt = 0; nt < 4; nt++) {
                acc2[mf][nt] = __builtin_amdgcn_mfma_f32_16x16x32_bf16(ah2[mf], bh[nt], acc2[mf][nt], 0, 0, 0);
                acc2[mf][nt] = __builtin_amdgcn_mfma_f32_16x16x32_bf16(ah2[mf], bl[nt], acc2[mf][nt], 0, 0, 0);
                acc2[mf][nt] = __builtin_amdgcn_mfma_f32_16x16x32_bf16(al2[mf], bh[nt], acc2[mf][nt], 0, 0, 0);
            }
#pragma unroll
        for (int mf = 0; mf < 4; mf++) { ah2[mf] = ahn[mf]; al2[mf] = aln[mf]; }
    }

    // ---- score epilogue ----
    float rpart = 0.f;
    float cpart[4] = {0.f, 0.f, 0.f, 0.f};
#pragma unroll
    for (int mf = 0; mf < 4; mf++) {
        int o = 64 * w + 16 * mf + q * 4;
#pragma unroll
        for (int r = 0; r < 4; r++) {
            float bias = b2[o + r];
            float wcv = w_col[(o + r) * N_ + hrow];
#pragma unroll
            for (int nt = 0; nt < 4; nt++) {
                int wc = nt * 16 + col;
                float v = fmaxf(acc2[mf][nt][r] + bias, 0.f);
                rpart += v * w_row[(o + r) * N_ + wc];
                cpart[nt] += v * wcv;
            }
        }
    }
#pragma unroll
    for (int off = 32; off; off >>= 1) rpart += __shfl_xor(rpart, off, 64);
    if (l == 0) atomicAdd(&row_red, rpart);
#pragma unroll
    for (int nt = 0; nt < 4; nt++) {
        float cp = cpart[nt];
        cp += __shfl_xor(cp, 16, 64);
        cp += __shfl_xor(cp, 32, 64);
        if (l < 16) atomicAdd(&col_red[nt * 16 + l], cp);
    }
    __syncthreads();
    if (t < 64) atomicAdd(&col_s[b * N_ + t], col_red[t]);
    if (t == 0) row_s[b * N_ + hrow] = b_row[0] + row_red;
}

// ---------------- K4: diff bitonic sort -> P as bf16 hi/lo ----------------
__global__ __launch_bounds__(256) void k4_diffsort(const float* __restrict__ row_s,
                                                   const float* __restrict__ col_s,
                                                   u16* __restrict__ prow_h, u16* __restrict__ prow_l,
                                                   u16* __restrict__ pcol_h, u16* __restrict__ pcol_l) {
    __shared__ float Ps[64 * 65];
    __shared__ float xs[64];
    __shared__ float als[32];
    const int t = threadIdx.x;
    const int which = blockIdx.x & 1;
    const int b = blockIdx.x >> 1;
    const float* sc = which ? col_s : row_s;
    u16* Ph = which ? pcol_h : prow_h;
    u16* Pl = which ? pcol_l : prow_l;

    if (t < 64) xs[t] = sc[b * 64 + t];
#pragma unroll
    for (int k = 0; k < 16; k++) {
        int idx = t + k * 256;
        int i = idx >> 6, j = idx & 63;
        Ps[i * 65 + j] = (i == j) ? 1.f : 0.f;
    }
    __syncthreads();

    const int r = t & 63, pg = t >> 6;
    for (int bl = 0; bl < 6; bl++) {
        for (int ly = 0; ly <= bl; ly++) {
            int sh = bl - ly;
            int m = 1 << sh;
            if (t < 32) {
                int i = (t >> sh) << (sh + 1);
                int j = t & (m - 1);
                int ix = i + j;
                int a = ix, bi = ix + m;
                if ((ix >> (bl + 1)) & 1) { int tmp = a; a = bi; bi = tmp; }
                float xa = xs[a], xbv = xs[bi];
                float al = atanf((xbv - xa) * STEEP) * INV_PI + 0.5f;
                als[t] = al;
                xs[a] = al * xa + (1.f - al) * xbv;
                xs[bi] = (1.f - al) * xa + al * xbv;
            }
            __syncthreads();
#pragma unroll
            for (int pi = 0; pi < 8; pi++) {
                int p = pg * 8 + pi;
                int i = (p >> sh) << (sh + 1);
                int j = p & (m - 1);
                int ix = i + j;
                int a = ix, bi = ix + m;
                if ((ix >> (bl + 1)) & 1) { int tmp = a; a = bi; bi = tmp; }
                float al = als[p];
                float Pa = Ps[r * 65 + a], Pb = Ps[r * 65 + bi];
                Ps[r * 65 + a] = al * Pa + (1.f - al) * Pb;
                Ps[r * 65 + bi] = (1.f - al) * Pa + al * Pb;
            }
            __syncthreads();
        }
    }
#pragma unroll
    for (int k = 0; k < 16; k++) {
        int idx = t + k * 256;
        int i = idx >> 6, j = idx & 63;
        float v = Ps[i * 65 + j];
        u16 h = f2bf(v);
        Ph[b * 4096 + idx] = h;
        Pl[b * 4096 + idx] = f2bf(v - bf2f(h));
    }
}

// ---------------- K5: fused double permutation via MFMA ----------------
__global__ __launch_bounds__(256) void k5_permute(const float* __restrict__ x,
                                                  const u16* __restrict__ pcol_h,
                                                  const u16* __restrict__ pcol_l,
                                                  const u16* __restrict__ prow_h,
                                                  const u16* __restrict__ prow_l,
                                                  float* __restrict__ out) {
    __shared__ __align__(16) u16 Xh[64 * LDX];
    __shared__ __align__(16) u16 Xl[64 * LDX];
    __shared__ __align__(16) u16 Zh[64 * LDX];
    __shared__ __align__(16) u16 Zl[64 * LDX];
    const int t = threadIdx.x;
    const int l = t & 63, w = t >> 6;
    const int col = l & 15, q = l >> 4;
    const int b = blockIdx.y;
    const int cbase = blockIdx.x * 4;
    const int i0 = w * 16;

    const u16* pch = pcol_h + (size_t)b * 4096;
    const u16* pcl = pcol_l + (size_t)b * 4096;
    const u16* prh = prow_h + (size_t)b * 4096;
    const u16* prl = prow_l + (size_t)b * 4096;

    bf16x8 pcA_h[2], pcA_l[2];
#pragma unroll
    for (int ks = 0; ks < 2; ks++) {
        pcA_h[ks] = *(const bf16x8*)&pch[(i0 + col) * 64 + q * 8 + ks * 32];
        pcA_l[ks] = *(const bf16x8*)&pcl[(i0 + col) * 64 + q * 8 + ks * 32];
    }

    for (int ci = 0; ci < 4; ci++) {
        const int c = cbase + ci;
        const float* xc = x + ((size_t)b * C_ + c) * PIX_;
#pragma unroll
        for (int k = 0; k < 4; k++) {
            int f = t + k * 256;
            int rw = f >> 4, c4 = f & 15;
            float4 v = *(const float4*)&xc[f * 4];
            u16 h0 = f2bf(v.x), h1 = f2bf(v.y), h2 = f2bf(v.z), h3 = f2bf(v.w);
            ushort4 hv = {h0, h1, h2, h3};
            ushort4 lv = {f2bf(v.x - bf2f(h0)), f2bf(v.y - bf2f(h1)),
                          f2bf(v.z - bf2f(h2)), f2bf(v.w - bf2f(h3))};
            *(ushort4*)&Xh[rw * LDX + c4 * 4] = hv;
            *(ushort4*)&Xl[rw * LDX + c4 * 4] = lv;
        }
        __syncthreads();

        f32x4 acc[4];
#pragma unroll
        for (int nt = 0; nt < 4; nt++) acc[nt] = (f32x4){0.f, 0.f, 0.f, 0.f};
#pragma unroll
        for (int ks = 0; ks < 2; ks++) {
            bf16x8 ah = pcA_h[ks], al_ = pcA_l[ks];
#pragma unroll
            for (int nt = 0; nt < 4; nt++) {
                bf16x8 bh = *(const bf16x8*)&Xh[(nt * 16 + col) * LDX + q * 8 + ks * 32];
                bf16x8 bl = *(const bf16x8*)&Xl[(nt * 16 + col) * LDX + q * 8 + ks * 32];
                acc[nt] = __builtin_amdgcn_mfma_f32_16x16x32_bf16(ah, bh, acc[nt], 0, 0, 0);
                acc[nt] = __builtin_amdgcn_mfma_f32_16x16x32_bf16(ah, bl, acc[nt], 0, 0, 0);
                acc[nt] = __builtin_amdgcn_mfma_f32_16x16x32_bf16(al_, bh, acc[nt], 0, 0, 0);
            }
        }
#pragma unroll
        for (int nt = 0; nt < 4; nt++)
#pragma unroll
            for (int r = 0; r < 4; r++) {
                float v = acc[nt][r];
                u16 h = f2bf(v);
                int rw = i0 + q * 4 + r;
                Zh[rw * LDX + nt * 16 + col] = h;
                Zl[rw * LDX + nt * 16 + col] = f2bf(v - bf2f(h));
            }

        f32x4 acc2[4];
#pragma unroll
        for (int nt = 0; nt < 4; nt++) acc2[nt] = (f32x4){0.f, 0.f, 0.f, 0.f};
#pragma unroll
        for (int ks = 0; ks < 2; ks++) {
            bf16x8 ah = *(const bf16x8*)&Zh[(i0 + col) * LDX + q * 8 + ks * 32];
            bf16x8 al_ = *(const bf16x8*)&Zl[(i0 + col) * LDX + q * 8 + ks * 32];
#pragma unroll
            for (int nt = 0; nt < 4; nt++) {
                bf16x8 bh = *(const bf16x8*)&prh[(nt * 16 + col) * 64 + q * 8 + ks * 32];
                bf16x8 bl = *(const bf16x8*)&prl[(nt * 16 + col) * 64 + q * 8 + ks * 32];
                acc2[nt] = __builtin_amdgcn_mfma_f32_16x16x32_bf16(ah, bh, acc2[nt], 0, 0, 0);
                acc2[nt] = __builtin_amdgcn_mfma_f32_16x16x32_bf16(ah, bl, acc2[nt], 0, 0, 0);
                acc2[nt] = __builtin_amdgcn_mfma_f32_16x16x32_bf16(al_, bh, acc2[nt], 0, 0, 0);
            }
        }
        float* oc = out + ((size_t)b * C_ + c) * PIX_;
#pragma unroll
        for (int nt = 0; nt < 4; nt++)
#pragma unroll
            for (int r = 0; r < 4; r++)
                oc[(i0 + q * 4 + r) * 64 + nt * 16 + col] = acc2[nt][r];
        __syncthreads();
    }
}

extern "C" void kernel_launch(void* const* d_in, const int* in_sizes, int n_in,
                              void* d_out, int out_size, void* d_ws, size_t ws_size,
                              hipStream_t stream) {
    const float* x = (const float*)d_in[0];
    const float* w1 = (const float*)d_in[1];
    const float* b1 = (const float*)d_in[2];
    const float* w2 = (const float*)d_in[3];
    const float* b2 = (const float*)d_in[4];
    const float* w_row = (const float*)d_in[5];
    const float* b_row = (const float*)d_in[6];
    const float* w_col = (const float*)d_in[7];
    const float* b_col = (const float*)d_in[8];
    float* out = (float*)d_out;

    char* ws = (char*)d_ws;
    u16* w1h = (u16*)(ws);                   //  65536 B
    u16* w1l = (u16*)(ws + 65536);           //  65536 B
    u16* w2h = (u16*)(ws + 131072);          //  131072 B
    u16* w2l = (u16*)(ws + 262144);          //  131072 B
    float* row_s = (float*)(ws + 393216);    //  8192 B
    float* col_s = (float*)(ws + 401408);    //  8192 B
    u16* prow_h = (u16*)(ws + 409600);       //  262144 B
    u16* prow_l = (u16*)(ws + 671744);       //  262144 B
    u16* pcol_h = (u16*)(ws + 933888);       //  262144 B
    u16* pcol_l = (u16*)(ws + 1196032);      //  262144 B

    hipLaunchKernelGGL(k0_init, dim3(8), dim3(256), 0, stream, col_s, b_col);
    hipLaunchKernelGGL(k_prep, dim3(384), dim3(256), 0, stream, w1, w2, w1h, w1l, w2h, w2l);
    hipLaunchKernelGGL(k12_fused, dim3(64, 32), dim3(256), 0, stream,
                       x, w1h, w1l, b1, w2h, w2l, b2, w_row, b_row, w_col, row_s, col_s);
    hipLaunchKernelGGL(k4_diffsort, dim3(64), dim3(256), 0, stream,
                       row_s, col_s, prow_h, prow_l, pcol_h, pcol_l);
    hipLaunchKernelGGL(k5_permute, dim3(32, 32), dim3(256), 0, stream,
                       x, pcol_h, pcol_l, prow_h, prow_l, out);
}